// Round 1
// baseline (403.562 us; speedup 1.0000x reference)
//
#include <hip/hip_runtime.h>
#include <hip/hip_bf16.h>
#include <stdint.h>

typedef __bf16 bf16;
typedef __bf16 bf16x8 __attribute__((ext_vector_type(8)));
typedef float  f32x4  __attribute__((ext_vector_type(4)));

#define MFMA16(A_, B_, C_) __builtin_amdgcn_mfma_f32_16x16x32_bf16((A_), (B_), (C_), 0, 0, 0)

__device__ __forceinline__ void gload_lds16(const void* g, void* l) {
  __builtin_amdgcn_global_load_lds(
      (const __attribute__((address_space(1))) unsigned int*)g,
      (__attribute__((address_space(3))) unsigned int*)l, 16, 0, 0);
}

// ---------------------------------------------------------------------------
// Weight transpose + fp32->bf16 convert:  out[n][k] = (bf16) in[k][n]
// in: [K][N] fp32 row-major, out: [N][K] bf16 row-major. 64x64 LDS tile.
// ---------------------------------------------------------------------------
__global__ __launch_bounds__(256) void wtrans(const float* __restrict__ in,
                                              bf16* __restrict__ out, int K, int N) {
  __shared__ bf16 tile[64][72];
  const int k0 = blockIdx.x * 64, n0 = blockIdx.y * 64;
  const int tid = threadIdx.x;
#pragma unroll
  for (int s = 0; s < 16; ++s) {
    int j = tid + s * 256;
    int r = j >> 6, c = j & 63;
    tile[r][c] = (bf16)in[(size_t)(k0 + r) * N + n0 + c];
  }
  __syncthreads();
#pragma unroll
  for (int s = 0; s < 16; ++s) {
    int j = tid + s * 256;
    int n = j >> 6, k = j & 63;
    out[(size_t)(n0 + n) * K + k0 + k] = tile[k][n];
  }
}

// pack bq|bk|bv -> bqkv[1536] fp32
__global__ void packbias(const float* __restrict__ bq, const float* __restrict__ bk,
                         const float* __restrict__ bv, float* __restrict__ bqkv) {
  int i = blockIdx.x * 256 + threadIdx.x;
  if (i < 1536) bqkv[i] = (i < 512) ? bq[i] : (i < 1024 ? bk[i - 512] : bv[i - 1024]);
}

// ---------------------------------------------------------------------------
// LayerNorm: x fp32 [4096][512] -> out bf16. One wave per row (64 lanes x 8).
// ---------------------------------------------------------------------------
__global__ __launch_bounds__(256) void ln_k(const float* __restrict__ x,
                                            const float* __restrict__ sc,
                                            const float* __restrict__ bi,
                                            bf16* __restrict__ out) {
  const int w = threadIdx.x >> 6, l = threadIdx.x & 63;
  const int row = blockIdx.x * 4 + w;
  const float4* xp = (const float4*)(x + (size_t)row * 512 + l * 8);
  float4 v0 = xp[0], v1 = xp[1];
  float xv[8] = {v0.x, v0.y, v0.z, v0.w, v1.x, v1.y, v1.z, v1.w};
  float s = 0.f, q = 0.f;
#pragma unroll
  for (int j = 0; j < 8; ++j) { s += xv[j]; q += xv[j] * xv[j]; }
#pragma unroll
  for (int m = 1; m < 64; m <<= 1) { s += __shfl_xor(s, m); q += __shfl_xor(q, m); }
  const float mean = s * (1.f / 512.f);
  const float var = q * (1.f / 512.f) - mean * mean;
  const float rstd = rsqrtf(var + 1e-6f);
  const float4* scp = (const float4*)(sc + l * 8);
  const float4* bip = (const float4*)(bi + l * 8);
  float4 s0 = scp[0], s1 = scp[1], b0 = bip[0], b1 = bip[1];
  float sv[8] = {s0.x, s0.y, s0.z, s0.w, s1.x, s1.y, s1.z, s1.w};
  float bv[8] = {b0.x, b0.y, b0.z, b0.w, b1.x, b1.y, b1.z, b1.w};
  bf16x8 ov;
#pragma unroll
  for (int j = 0; j < 8; ++j) ov[j] = (bf16)((xv[j] - mean) * rstd * sv[j] + bv[j]);
  *(bf16x8*)(out + (size_t)row * 512 + l * 8) = ov;
}

// ---------------------------------------------------------------------------
// GEMM: C[M][N] = A[M][K] @ Bt[N][K]^T + bias, epilogues:
//  EPI 0: +bias -> bf16     EPI 1: +bias +res(fp32) -> fp32     EPI 2: +bias, gelu -> bf16
// 128x128 block tile, BK=32, 4 waves (2x2), 64x64 per wave, mfma 16x16x32 bf16.
// M,N,K all multiples of 128/32 (no edge handling).
// ---------------------------------------------------------------------------
template <int EPI>
__global__ __launch_bounds__(256) void gemm_bt(const bf16* __restrict__ A,
                                               const bf16* __restrict__ Bt,
                                               const float* __restrict__ bias,
                                               const float* __restrict__ res,
                                               void* __restrict__ outp,
                                               int M, int N, int K) {
  __shared__ bf16 a_lds[128 * 32];
  __shared__ bf16 b_lds[128 * 32];
  const int m0 = blockIdx.x * 128, n0 = blockIdx.y * 128;
  const int tid = threadIdx.x, l = tid & 63, w = tid >> 6;
  const int wm = w >> 1, wn = w & 1;
  const int lc = l & 15, g = l >> 4;

  f32x4 acc[4][4] = {};

  const int kiters = K >> 5;
  for (int kt = 0; kt < kiters; ++kt) {
    const int k0 = kt << 5;
    // stage A and Bt tiles: each wave 2 rounds x 16 rows, 16B/lane, linear LDS
#pragma unroll
    for (int r = 0; r < 2; ++r) {
      const int row = r * 64 + w * 16 + (l >> 2);
      const int c8 = (l & 3) * 8;
      gload_lds16(A + (size_t)(m0 + row) * K + k0 + c8,
                  (char*)a_lds + (r * 64 + w * 16) * 64);
      gload_lds16(Bt + (size_t)(n0 + row) * K + k0 + c8,
                  (char*)b_lds + (r * 64 + w * 16) * 64);
    }
    __syncthreads();  // drains vmcnt before barrier -> tiles complete

    bf16x8 af[4], bfr[4];
#pragma unroll
    for (int i = 0; i < 4; ++i) {
      af[i]  = *(const bf16x8*)(a_lds + (wm * 64 + i * 16 + lc) * 32 + g * 8);
      bfr[i] = *(const bf16x8*)(b_lds + (wn * 64 + i * 16 + lc) * 32 + g * 8);
    }
#pragma unroll
    for (int mi = 0; mi < 4; ++mi)
#pragma unroll
      for (int ni = 0; ni < 4; ++ni)
        acc[mi][ni] = MFMA16(af[mi], bfr[ni], acc[mi][ni]);
    __syncthreads();  // compute done before next-tile overwrite
  }

#pragma unroll
  for (int mi = 0; mi < 4; ++mi)
#pragma unroll
    for (int ni = 0; ni < 4; ++ni) {
      const int col = n0 + wn * 64 + ni * 16 + lc;
      const float bb = bias[col];
#pragma unroll
      for (int i = 0; i < 4; ++i) {
        const int row = m0 + wm * 64 + mi * 16 + g * 4 + i;
        float v = acc[mi][ni][i] + bb;
        if constexpr (EPI == 0) {
          ((bf16*)outp)[(size_t)row * N + col] = (bf16)v;
        } else if constexpr (EPI == 1) {
          ((float*)outp)[(size_t)row * N + col] = v + res[(size_t)row * N + col];
        } else {
          float t = 0.7978845608028654f * (v + 0.044715f * v * v * v);
          float gl = 0.5f * v * (1.f + tanhf(t));
          ((bf16*)outp)[(size_t)row * N + col] = (bf16)gl;
        }
      }
    }
}

// ---------------------------------------------------------------------------
// V transpose: qkv[t][1024 + h*64 + d] -> vt[h][d][t]   (bf16)
// ---------------------------------------------------------------------------
__global__ __launch_bounds__(256) void vtrans(const bf16* __restrict__ qkv,
                                              bf16* __restrict__ vt) {
  __shared__ bf16 tile[64][72];
  const int t0 = blockIdx.x * 64;
  const int head = blockIdx.y;
  const int tid = threadIdx.x;
#pragma unroll
  for (int s = 0; s < 16; ++s) {
    int j = tid + s * 256;
    int t = j >> 6, c = j & 63;
    tile[t][c] = qkv[(size_t)(t0 + t) * 1536 + 1024 + head * 64 + c];
  }
  __syncthreads();
#pragma unroll
  for (int s = 0; s < 16; ++s) {
    int j = tid + s * 256;
    int d = j >> 6, t = j & 63;
    vt[(size_t)head * 64 * 4096 + (size_t)d * 4096 + t0 + t] = tile[t][d];
  }
}

// ---------------------------------------------------------------------------
// Flash attention. Block = (head, 64 q-rows), 4 waves x 16 rows each.
// qkv: [4096][1536] bf16 (q|k|v), vt: [8][64][4096] bf16, out: [4096][512] bf16.
// Online softmax; P relayout via per-wave padded LDS tile; 16x16x32 MFMA.
// Both MFMA operands always load contiguous-8 along K -> k-permutation cancels.
// ---------------------------------------------------------------------------
__global__ __launch_bounds__(256) void attn_k(const bf16* __restrict__ qkv,
                                              const bf16* __restrict__ vt,
                                              bf16* __restrict__ out) {
  constexpr float LOG2E = 1.44269504088896f;
  const int bid = blockIdx.x;
  const int head = bid & 7;      // head == bid%8 -> one head per XCD (L2 locality)
  const int qt = bid >> 3;
  const int w = threadIdx.x >> 6, l = threadIdx.x & 63;
  const int g = l >> 4, lc = l & 15;
  const int qrow0 = qt * 64 + w * 16;

  __shared__ bf16 p_lds[4][16][72];
  bf16* pw = &p_lds[w][0][0];

  // Q fragments for this wave's 16 rows (rows qrow0+lc), hd=64 -> 2 k-chunks
  const bf16* qbase = qkv + (size_t)(qrow0 + lc) * 1536 + head * 64;
  bf16x8 qf[2];
  qf[0] = *(const bf16x8*)(qbase + g * 8);
  qf[1] = *(const bf16x8*)(qbase + 32 + g * 8);

  const bf16* kbase = qkv + 512 + head * 64;
  const bf16* vb = vt + (size_t)head * 64 * 4096;

  f32x4 o[4] = {};
  float m_i[4], ell[4];
#pragma unroll
  for (int i = 0; i < 4; ++i) { m_i[i] = -1e30f; ell[i] = 0.f; }

  for (int kt = 0; kt < 64; ++kt) {
    const int kv0 = kt * 64;
    f32x4 s[4] = {};
#pragma unroll
    for (int scc = 0; scc < 4; ++scc) {
      const bf16* kb = kbase + (size_t)(kv0 + scc * 16 + lc) * 1536 + g * 8;
      bf16x8 kf0 = *(const bf16x8*)(kb);
      bf16x8 kf1 = *(const bf16x8*)(kb + 32);
      s[scc] = MFMA16(qf[0], kf0, s[scc]);
      s[scc] = MFMA16(qf[1], kf1, s[scc]);
    }
    // scale 1/sqrt(64)
#pragma unroll
    for (int scc = 0; scc < 4; ++scc)
#pragma unroll
      for (int i = 0; i < 4; ++i) s[scc][i] *= 0.125f;

    // per-row tile max (row i lives on 16 lanes sharing g)
    float tmax[4];
#pragma unroll
    for (int i = 0; i < 4; ++i)
      tmax[i] = fmaxf(fmaxf(s[0][i], s[1][i]), fmaxf(s[2][i], s[3][i]));
#pragma unroll
    for (int i = 0; i < 4; ++i) {
      tmax[i] = fmaxf(tmax[i], __shfl_xor(tmax[i], 1));
      tmax[i] = fmaxf(tmax[i], __shfl_xor(tmax[i], 2));
      tmax[i] = fmaxf(tmax[i], __shfl_xor(tmax[i], 4));
      tmax[i] = fmaxf(tmax[i], __shfl_xor(tmax[i], 8));
    }
    float fac[4], psum[4];
#pragma unroll
    for (int i = 0; i < 4; ++i) {
      float mn = fmaxf(m_i[i], tmax[i]);
      fac[i] = exp2f((m_i[i] - mn) * LOG2E);
      m_i[i] = mn;
      psum[i] = 0.f;
    }
    // P = exp(s - m), write bf16 into per-wave LDS tile [16 rows][64 keys] pad 72
#pragma unroll
    for (int scc = 0; scc < 4; ++scc)
#pragma unroll
      for (int i = 0; i < 4; ++i) {
        float p = exp2f((s[scc][i] - m_i[i]) * LOG2E);
        psum[i] += p;
        pw[(g * 4 + i) * 72 + scc * 16 + lc] = (bf16)p;
      }
#pragma unroll
    for (int i = 0; i < 4; ++i) {
      float ps = psum[i];
      ps += __shfl_xor(ps, 1); ps += __shfl_xor(ps, 2);
      ps += __shfl_xor(ps, 4); ps += __shfl_xor(ps, 8);
      ell[i] = ell[i] * fac[i] + ps;
    }
#pragma unroll
    for (int dc = 0; dc < 4; ++dc)
#pragma unroll
      for (int i = 0; i < 4; ++i) o[dc][i] *= fac[i];

    // O += P @ V   (A = P from LDS, B = Vt rows, both contiguous-8 along keys)
#pragma unroll
    for (int kc = 0; kc < 2; ++kc) {
      bf16x8 pa = *(const bf16x8*)(pw + lc * 72 + kc * 32 + g * 8);
#pragma unroll
      for (int dc = 0; dc < 4; ++dc) {
        bf16x8 vv = *(const bf16x8*)(vb + (size_t)(dc * 16 + lc) * 4096 + kv0 + kc * 32 + g * 8);
        o[dc] = MFMA16(pa, vv, o[dc]);
      }
    }
  }

  bf16* ob = out + (size_t)qrow0 * 512 + head * 64;
#pragma unroll
  for (int i = 0; i < 4; ++i) {
    float inv = 1.f / ell[i];
#pragma unroll
    for (int dc = 0; dc < 4; ++dc)
      ob[(size_t)(g * 4 + i) * 512 + dc * 16 + lc] = (bf16)(o[dc][i] * inv);
  }
}

// ---------------------------------------------------------------------------
extern "C" void kernel_launch(void* const* d_in, const int* in_sizes, int n_in,
                              void* d_out, int out_size, void* d_ws, size_t ws_size,
                              hipStream_t stream) {
  const float* x    = (const float*)d_in[0];
  const float* ln1s = (const float*)d_in[1];
  const float* ln1b = (const float*)d_in[2];
  const float* Wq   = (const float*)d_in[3];
  const float* bq   = (const float*)d_in[4];
  const float* Wk   = (const float*)d_in[5];
  const float* bk   = (const float*)d_in[6];
  const float* Wv   = (const float*)d_in[7];
  const float* bv   = (const float*)d_in[8];
  const float* Wo   = (const float*)d_in[9];
  const float* bo   = (const float*)d_in[10];
  const float* ln2s = (const float*)d_in[11];
  const float* ln2b = (const float*)d_in[12];
  const float* W1   = (const float*)d_in[13];
  const float* b1   = (const float*)d_in[14];
  const float* W2   = (const float*)d_in[15];
  const float* b2   = (const float*)d_in[16];
  float* out = (float*)d_out;

  char* ws = (char*)d_ws;
  bf16* wqkvT = (bf16*)(ws + 0);               // [1536][512]   1.5 MB
  bf16* woT   = (bf16*)(ws + 1572864);         // [512][512]    0.5 MB
  bf16* w1T   = (bf16*)(ws + 2097152);         // [2048][512]   2 MB
  bf16* w2T   = (bf16*)(ws + 4194304);         // [512][2048]   2 MB
  float* bqkv = (float*)(ws + 6291456);        // [1536]
  float* x2   = (float*)(ws + 6299648);        // [4096][512] fp32  8 MB
  bf16* h     = (bf16*)(ws + 14688256);        // [4096][512]   4 MB (reused as h2)
  bf16* qkv   = (bf16*)(ws + 18882560);        // [4096][1536] 12 MB (reused for gbuf)
  bf16* vt    = (bf16*)(ws + 31465472);        // [8][64][4096] 4 MB
  bf16* attnb = (bf16*)(ws + 35659776);        // [4096][512]   4 MB   (end ~40 MB)
  bf16* h2   = h;
  bf16* gbuf = qkv;  // [4096][2048] 16 MB, overlaps qkv+vt (both dead by then)

  // weight prep
  wtrans<<<dim3(8, 8),  256, 0, stream>>>(Wq, wqkvT,               512, 512);
  wtrans<<<dim3(8, 8),  256, 0, stream>>>(Wk, wqkvT + 512 * 512,   512, 512);
  wtrans<<<dim3(8, 8),  256, 0, stream>>>(Wv, wqkvT + 1024 * 512,  512, 512);
  wtrans<<<dim3(8, 8),  256, 0, stream>>>(Wo, woT,                 512, 512);
  wtrans<<<dim3(8, 32), 256, 0, stream>>>(W1, w1T,                 512, 2048);
  wtrans<<<dim3(32, 8), 256, 0, stream>>>(W2, w2T,                 2048, 512);
  packbias<<<6, 256, 0, stream>>>(bq, bk, bv, bqkv);

  // block
  ln_k<<<1024, 256, 0, stream>>>(x, ln1s, ln1b, h);
  gemm_bt<0><<<dim3(32, 12), 256, 0, stream>>>(h, wqkvT, bqkv, nullptr, qkv, 4096, 1536, 512);
  vtrans<<<dim3(64, 8), 256, 0, stream>>>(qkv, vt);
  attn_k<<<512, 256, 0, stream>>>(qkv, vt, attnb);
  gemm_bt<1><<<dim3(32, 4), 256, 0, stream>>>(attnb, woT, bo, x, x2, 4096, 512, 512);
  ln_k<<<1024, 256, 0, stream>>>(x2, ln2s, ln2b, h2);
  gemm_bt<2><<<dim3(32, 16), 256, 0, stream>>>(h2, w1T, b1, nullptr, gbuf, 4096, 2048, 512);
  gemm_bt<1><<<dim3(32, 4), 256, 0, stream>>>(gbuf, w2T, b2, x2, out, 4096, 512, 2048);
}

// Round 2
// 225.885 us; speedup vs baseline: 1.7866x; 1.7866x over previous
//
#include <hip/hip_runtime.h>
#include <hip/hip_bf16.h>
#include <stdint.h>

typedef __bf16 bf16;
typedef __bf16 bf16x8 __attribute__((ext_vector_type(8)));
typedef float  f32x4  __attribute__((ext_vector_type(4)));

#define MFMA16(A_, B_, C_) __builtin_amdgcn_mfma_f32_16x16x32_bf16((A_), (B_), (C_), 0, 0, 0)

__device__ __forceinline__ void gload_lds16(const void* g, void* l) {
  __builtin_amdgcn_global_load_lds(
      (const __attribute__((address_space(1))) unsigned int*)g,
      (__attribute__((address_space(3))) unsigned int*)l, 16, 0, 0);
}

// ---------------------------------------------------------------------------
// Weight transpose + fp32->bf16 convert:  out[n][k] = (bf16) in[k][n]
// ---------------------------------------------------------------------------
__global__ __launch_bounds__(256) void wtrans(const float* __restrict__ in,
                                              bf16* __restrict__ out, int K, int N) {
  __shared__ bf16 tile[64][72];
  const int k0 = blockIdx.x * 64, n0 = blockIdx.y * 64;
  const int tid = threadIdx.x;
#pragma unroll
  for (int s = 0; s < 16; ++s) {
    int j = tid + s * 256;
    int r = j >> 6, c = j & 63;
    tile[r][c] = (bf16)in[(size_t)(k0 + r) * N + n0 + c];
  }
  __syncthreads();
#pragma unroll
  for (int s = 0; s < 16; ++s) {
    int j = tid + s * 256;
    int n = j >> 6, k = j & 63;
    out[(size_t)(n0 + n) * K + k0 + k] = tile[k][n];
  }
}

// pack bq|bk|bv -> bqkv[1536] fp32
__global__ void packbias(const float* __restrict__ bq, const float* __restrict__ bk,
                         const float* __restrict__ bv, float* __restrict__ bqkv) {
  int i = blockIdx.x * 256 + threadIdx.x;
  if (i < 1536) bqkv[i] = (i < 512) ? bq[i] : (i < 1024 ? bk[i - 512] : bv[i - 1024]);
}

// ---------------------------------------------------------------------------
// LayerNorm: x fp32 [4096][512] -> out bf16. One wave per row.
// ---------------------------------------------------------------------------
__global__ __launch_bounds__(256) void ln_k(const float* __restrict__ x,
                                            const float* __restrict__ sc,
                                            const float* __restrict__ bi,
                                            bf16* __restrict__ out) {
  const int w = threadIdx.x >> 6, l = threadIdx.x & 63;
  const int row = blockIdx.x * 4 + w;
  const float4* xp = (const float4*)(x + (size_t)row * 512 + l * 8);
  float4 v0 = xp[0], v1 = xp[1];
  float xv[8] = {v0.x, v0.y, v0.z, v0.w, v1.x, v1.y, v1.z, v1.w};
  float s = 0.f, q = 0.f;
#pragma unroll
  for (int j = 0; j < 8; ++j) { s += xv[j]; q += xv[j] * xv[j]; }
#pragma unroll
  for (int m = 1; m < 64; m <<= 1) { s += __shfl_xor(s, m); q += __shfl_xor(q, m); }
  const float mean = s * (1.f / 512.f);
  const float var = q * (1.f / 512.f) - mean * mean;
  const float rstd = rsqrtf(var + 1e-6f);
  const float4* scp = (const float4*)(sc + l * 8);
  const float4* bip = (const float4*)(bi + l * 8);
  float4 s0 = scp[0], s1 = scp[1], b0 = bip[0], b1 = bip[1];
  float sv[8] = {s0.x, s0.y, s0.z, s0.w, s1.x, s1.y, s1.z, s1.w};
  float bv[8] = {b0.x, b0.y, b0.z, b0.w, b1.x, b1.y, b1.z, b1.w};
  bf16x8 ov;
#pragma unroll
  for (int j = 0; j < 8; ++j) ov[j] = (bf16)((xv[j] - mean) * rstd * sv[j] + bv[j]);
  *(bf16x8*)(out + (size_t)row * 512 + l * 8) = ov;
}

// ---------------------------------------------------------------------------
// GEMM: C[M][N] = A[M][K] @ Bt[N][K]^T + bias (epilogues as before)
// ---------------------------------------------------------------------------
template <int EPI>
__global__ __launch_bounds__(256) void gemm_bt(const bf16* __restrict__ A,
                                               const bf16* __restrict__ Bt,
                                               const float* __restrict__ bias,
                                               const float* __restrict__ res,
                                               void* __restrict__ outp,
                                               int M, int N, int K) {
  __shared__ bf16 a_lds[128 * 32];
  __shared__ bf16 b_lds[128 * 32];
  const int m0 = blockIdx.x * 128, n0 = blockIdx.y * 128;
  const int tid = threadIdx.x, l = tid & 63, w = tid >> 6;
  const int wm = w >> 1, wn = w & 1;
  const int lc = l & 15, g = l >> 4;

  f32x4 acc[4][4] = {};

  const int kiters = K >> 5;
  for (int kt = 0; kt < kiters; ++kt) {
    const int k0 = kt << 5;
#pragma unroll
    for (int r = 0; r < 2; ++r) {
      const int row = r * 64 + w * 16 + (l >> 2);
      const int c8 = (l & 3) * 8;
      gload_lds16(A + (size_t)(m0 + row) * K + k0 + c8,
                  (char*)a_lds + (r * 64 + w * 16) * 64);
      gload_lds16(Bt + (size_t)(n0 + row) * K + k0 + c8,
                  (char*)b_lds + (r * 64 + w * 16) * 64);
    }
    __syncthreads();

    bf16x8 af[4], bfr[4];
#pragma unroll
    for (int i = 0; i < 4; ++i) {
      af[i]  = *(const bf16x8*)(a_lds + (wm * 64 + i * 16 + lc) * 32 + g * 8);
      bfr[i] = *(const bf16x8*)(b_lds + (wn * 64 + i * 16 + lc) * 32 + g * 8);
    }
#pragma unroll
    for (int mi = 0; mi < 4; ++mi)
#pragma unroll
      for (int ni = 0; ni < 4; ++ni)
        acc[mi][ni] = MFMA16(af[mi], bfr[ni], acc[mi][ni]);
    __syncthreads();
  }

#pragma unroll
  for (int mi = 0; mi < 4; ++mi)
#pragma unroll
    for (int ni = 0; ni < 4; ++ni) {
      const int col = n0 + wn * 64 + ni * 16 + lc;
      const float bb = bias[col];
#pragma unroll
      for (int i = 0; i < 4; ++i) {
        const int row = m0 + wm * 64 + mi * 16 + g * 4 + i;
        float v = acc[mi][ni][i] + bb;
        if constexpr (EPI == 0) {
          ((bf16*)outp)[(size_t)row * N + col] = (bf16)v;
        } else if constexpr (EPI == 1) {
          ((float*)outp)[(size_t)row * N + col] = v + res[(size_t)row * N + col];
        } else {
          float t = 0.7978845608028654f * (v + 0.044715f * v * v * v);
          float gl = 0.5f * v * (1.f + tanhf(t));
          ((bf16*)outp)[(size_t)row * N + col] = (bf16)gl;
        }
      }
    }
}

// ---------------------------------------------------------------------------
// V transpose: qkv[t][1024 + h*64 + d] -> vt[h][d][t]   (bf16)
// ---------------------------------------------------------------------------
__global__ __launch_bounds__(256) void vtrans(const bf16* __restrict__ qkv,
                                              bf16* __restrict__ vt) {
  __shared__ bf16 tile[64][72];
  const int t0 = blockIdx.x * 64;
  const int head = blockIdx.y;
  const int tid = threadIdx.x;
#pragma unroll
  for (int s = 0; s < 16; ++s) {
    int j = tid + s * 256;
    int t = j >> 6, c = j & 63;
    tile[t][c] = qkv[(size_t)(t0 + t) * 1536 + 1024 + head * 64 + c];
  }
  __syncthreads();
#pragma unroll
  for (int s = 0; s < 16; ++s) {
    int j = tid + s * 256;
    int d = j >> 6, t = j & 63;
    vt[(size_t)head * 64 * 4096 + (size_t)d * 4096 + t0 + t] = tile[t][d];
  }
}

// ---------------------------------------------------------------------------
// Flash attention, v2. Block = (head, 64 q-rows), 4 waves x 16 rows.
// K,V tiles LDS-staged (double-buffered, global_load_lds w=16, source-side
// XOR swizzle chunk^=(row&7) so ds_read_b128 frags are conflict-free).
// Constant-max softmax: P = exp2(S*0.125*log2e - 8*log2e); row-sum ell
// accumulated per-lane, reduced ONCE after the loop. No per-iter shuffles.
// P relayout via per-wave swizzled LDS tile [16][64].
// ---------------------------------------------------------------------------
__global__ __launch_bounds__(256) void attn_k(const bf16* __restrict__ qkv,
                                              const bf16* __restrict__ vt,
                                              bf16* __restrict__ out) {
  const int bid = blockIdx.x;
  const int head = bid & 7;     // one head per XCD (L2 locality)
  const int qt = bid >> 3;
  const int w = threadIdx.x >> 6, l = threadIdx.x & 63;
  const int g = l >> 4, lc = l & 15;
  const int qrow0 = qt * 64 + w * 16;

  __shared__ bf16 k_lds[2][64 * 64];
  __shared__ bf16 v_lds[2][64 * 64];
  __shared__ bf16 p_all[4][16 * 64];
  bf16* pw = p_all[w];

  // Q fragments (rows qrow0+lc), hd=64 -> 2 k-chunks
  const bf16* qb = qkv + (size_t)(qrow0 + lc) * 1536 + head * 64;
  bf16x8 qf0 = *(const bf16x8*)(qb + g * 8);
  bf16x8 qf1 = *(const bf16x8*)(qb + 32 + g * 8);

  const bf16* kg = qkv + 512 + head * 64;          // K rows, stride 1536
  const bf16* vg = vt + (size_t)head * 64 * 4096;  // Vt rows (d), stride 4096

  const int srow = l >> 3;          // row within wave's 8-row staging group
  const int cs = (l & 7) ^ srow;    // pre-swizzled source chunk

  f32x4 o[4] = {};
  float psum[4] = {0.f, 0.f, 0.f, 0.f};

  // prologue: stage kt=0 into buf 0
#pragma unroll
  for (int j = 0; j < 2; ++j) {
    const int row = j * 32 + w * 8 + srow;
    gload_lds16(kg + (size_t)row * 1536 + cs * 8,
                (char*)k_lds[0] + (j * 32 + w * 8) * 128);
    gload_lds16(vg + (size_t)row * 4096 + cs * 8,
                (char*)v_lds[0] + (j * 32 + w * 8) * 128);
  }
  __syncthreads();

  constexpr float C1 = 0.125f * 1.44269504088896f;  // 1/sqrt(64) * log2(e)
  constexpr float C0 = -8.0f * 1.44269504088896f;   // -(const max) * log2(e)

  for (int kt = 0; kt < 64; ++kt) {
    const int cur = kt & 1;
    if (kt < 63) {  // stage next tile into the other buffer
      const int kv0 = (kt + 1) * 64;
#pragma unroll
      for (int j = 0; j < 2; ++j) {
        const int row = j * 32 + w * 8 + srow;
        gload_lds16(kg + (size_t)(kv0 + row) * 1536 + cs * 8,
                    (char*)k_lds[cur ^ 1] + (j * 32 + w * 8) * 128);
        gload_lds16(vg + (size_t)row * 4096 + kv0 + cs * 8,
                    (char*)v_lds[cur ^ 1] + (j * 32 + w * 8) * 128);
      }
    }
    const bf16* kb = k_lds[cur];
    const bf16* vb = v_lds[cur];

    // QK^T: S[q=g*4+i][key=scc*16+lc]
    f32x4 s[4] = {};
#pragma unroll
    for (int scc = 0; scc < 4; ++scc) {
      const int row = scc * 16 + lc;
      bf16x8 kf0 = *(const bf16x8*)(kb + row * 64 + ((0 + g) ^ (lc & 7)) * 8);
      bf16x8 kf1 = *(const bf16x8*)(kb + row * 64 + ((4 + g) ^ (lc & 7)) * 8);
      s[scc] = MFMA16(qf0, kf0, s[scc]);
      s[scc] = MFMA16(qf1, kf1, s[scc]);
    }

    // P = exp2(S*C1 + C0); accumulate row-sum per-lane; store swizzled bf16
#pragma unroll
    for (int scc = 0; scc < 4; ++scc) {
      const int chunk = scc * 2 + (lc >> 3);
#pragma unroll
      for (int i = 0; i < 4; ++i) {
        float p = exp2f(s[scc][i] * C1 + C0);
        psum[i] += p;
        const int q = g * 4 + i;
        pw[q * 64 + (chunk ^ (q & 7)) * 8 + (lc & 7)] = (bf16)p;
      }
    }

    // O += P @ V
#pragma unroll
    for (int kc = 0; kc < 2; ++kc) {
      bf16x8 pa = *(const bf16x8*)(pw + lc * 64 + ((kc * 4 + g) ^ (lc & 7)) * 8);
#pragma unroll
      for (int dc = 0; dc < 4; ++dc) {
        const int row = dc * 16 + lc;
        bf16x8 vv = *(const bf16x8*)(vb + row * 64 + ((kc * 4 + g) ^ (lc & 7)) * 8);
        o[dc] = MFMA16(pa, vv, o[dc]);
      }
    }
    __syncthreads();  // stage for kt+1 drained; everyone done with buf[cur]
  }

  bf16* ob = out + (size_t)qrow0 * 512 + head * 64;
#pragma unroll
  for (int i = 0; i < 4; ++i) {
    float ps = psum[i];
    ps += __shfl_xor(ps, 1); ps += __shfl_xor(ps, 2);
    ps += __shfl_xor(ps, 4); ps += __shfl_xor(ps, 8);
    const float inv = 1.f / ps;
#pragma unroll
    for (int dc = 0; dc < 4; ++dc)
      ob[(size_t)(g * 4 + i) * 512 + dc * 16 + lc] = (bf16)(o[dc][i] * inv);
  }
}

// ---------------------------------------------------------------------------
extern "C" void kernel_launch(void* const* d_in, const int* in_sizes, int n_in,
                              void* d_out, int out_size, void* d_ws, size_t ws_size,
                              hipStream_t stream) {
  const float* x    = (const float*)d_in[0];
  const float* ln1s = (const float*)d_in[1];
  const float* ln1b = (const float*)d_in[2];
  const float* Wq   = (const float*)d_in[3];
  const float* bq   = (const float*)d_in[4];
  const float* Wk   = (const float*)d_in[5];
  const float* bk   = (const float*)d_in[6];
  const float* Wv   = (const float*)d_in[7];
  const float* bv   = (const float*)d_in[8];
  const float* Wo   = (const float*)d_in[9];
  const float* bo   = (const float*)d_in[10];
  const float* ln2s = (const float*)d_in[11];
  const float* ln2b = (const float*)d_in[12];
  const float* W1   = (const float*)d_in[13];
  const float* b1   = (const float*)d_in[14];
  const float* W2   = (const float*)d_in[15];
  const float* b2   = (const float*)d_in[16];
  float* out = (float*)d_out;

  char* ws = (char*)d_ws;
  bf16* wqkvT = (bf16*)(ws + 0);               // [1536][512]   1.5 MB
  bf16* woT   = (bf16*)(ws + 1572864);         // [512][512]    0.5 MB
  bf16* w1T   = (bf16*)(ws + 2097152);         // [2048][512]   2 MB
  bf16* w2T   = (bf16*)(ws + 4194304);         // [512][2048]   2 MB
  float* bqkv = (float*)(ws + 6291456);        // [1536]
  float* x2   = (float*)(ws + 6299648);        // [4096][512] fp32  8 MB
  bf16* h     = (bf16*)(ws + 14688256);        // [4096][512]   4 MB (reused as h2)
  bf16* qkv   = (bf16*)(ws + 18882560);        // [4096][1536] 12 MB (reused for gbuf)
  bf16* vt    = (bf16*)(ws + 31465472);        // [8][64][4096] 4 MB
  bf16* attnb = (bf16*)(ws + 35659776);        // [4096][512]   4 MB
  bf16* h2   = h;
  bf16* gbuf = qkv;  // [4096][2048] 16 MB, overlaps qkv+vt (both dead by then)

  // weight prep
  wtrans<<<dim3(8, 8),  256, 0, stream>>>(Wq, wqkvT,               512, 512);
  wtrans<<<dim3(8, 8),  256, 0, stream>>>(Wk, wqkvT + 512 * 512,   512, 512);
  wtrans<<<dim3(8, 8),  256, 0, stream>>>(Wv, wqkvT + 1024 * 512,  512, 512);
  wtrans<<<dim3(8, 8),  256, 0, stream>>>(Wo, woT,                 512, 512);
  wtrans<<<dim3(8, 32), 256, 0, stream>>>(W1, w1T,                 512, 2048);
  wtrans<<<dim3(32, 8), 256, 0, stream>>>(W2, w2T,                 2048, 512);
  packbias<<<6, 256, 0, stream>>>(bq, bk, bv, bqkv);

  // block
  ln_k<<<1024, 256, 0, stream>>>(x, ln1s, ln1b, h);
  gemm_bt<0><<<dim3(32, 12), 256, 0, stream>>>(h, wqkvT, bqkv, nullptr, qkv, 4096, 1536, 512);
  vtrans<<<dim3(64, 8), 256, 0, stream>>>(qkv, vt);
  attn_k<<<512, 256, 0, stream>>>(qkv, vt, attnb);
  gemm_bt<1><<<dim3(32, 4), 256, 0, stream>>>(attnb, woT, bo, x, x2, 4096, 512, 512);
  ln_k<<<1024, 256, 0, stream>>>(x2, ln2s, ln2b, h2);
  gemm_bt<2><<<dim3(32, 16), 256, 0, stream>>>(h2, w1T, b1, nullptr, gbuf, 4096, 2048, 512);
  gemm_bt<1><<<dim3(32, 4), 256, 0, stream>>>(gbuf, w2T, b2, x2, out, 4096, 512, 2048);
}

// Round 3
// 197.159 us; speedup vs baseline: 2.0469x; 1.1457x over previous
//
#include <hip/hip_runtime.h>
#include <hip/hip_bf16.h>
#include <stdint.h>

typedef __bf16 bf16;
typedef __bf16 bf16x4 __attribute__((ext_vector_type(4)));
typedef __bf16 bf16x8 __attribute__((ext_vector_type(8)));
typedef float  f32x4  __attribute__((ext_vector_type(4)));
typedef float  f32x16 __attribute__((ext_vector_type(16)));

#define MFMA16(A_, B_, C_) __builtin_amdgcn_mfma_f32_16x16x32_bf16((A_), (B_), (C_), 0, 0, 0)
#define MFMA32(A_, B_, C_) __builtin_amdgcn_mfma_f32_32x32x16_bf16((A_), (B_), (C_), 0, 0, 0)

__device__ __forceinline__ void gload_lds16(const void* g, void* l) {
  __builtin_amdgcn_global_load_lds(
      (const __attribute__((address_space(1))) unsigned int*)g,
      (__attribute__((address_space(3))) unsigned int*)l, 16, 0, 0);
}

__device__ __forceinline__ unsigned pk2(float lo, float hi_) {
  union { bf16 h[2]; unsigned u; } t;
  t.h[0] = (bf16)lo; t.h[1] = (bf16)hi_;
  return t.u;
}

// ---------------------------------------------------------------------------
// Weight transpose + fp32->bf16 convert:  out[n][k] = (bf16) in[k][n]
// ---------------------------------------------------------------------------
__global__ __launch_bounds__(256) void wtrans(const float* __restrict__ in,
                                              bf16* __restrict__ out, int K, int N) {
  __shared__ bf16 tile[64][72];
  const int k0 = blockIdx.x * 64, n0 = blockIdx.y * 64;
  const int tid = threadIdx.x;
#pragma unroll
  for (int s = 0; s < 16; ++s) {
    int j = tid + s * 256;
    int r = j >> 6, c = j & 63;
    tile[r][c] = (bf16)in[(size_t)(k0 + r) * N + n0 + c];
  }
  __syncthreads();
#pragma unroll
  for (int s = 0; s < 16; ++s) {
    int j = tid + s * 256;
    int n = j >> 6, k = j & 63;
    out[(size_t)(n0 + n) * K + k0 + k] = tile[k][n];
  }
}

// pack bq|bk|bv -> bqkv[1536] fp32
__global__ void packbias(const float* __restrict__ bq, const float* __restrict__ bk,
                         const float* __restrict__ bv, float* __restrict__ bqkv) {
  int i = blockIdx.x * 256 + threadIdx.x;
  if (i < 1536) bqkv[i] = (i < 512) ? bq[i] : (i < 1024 ? bk[i - 512] : bv[i - 1024]);
}

// ---------------------------------------------------------------------------
// LayerNorm: x fp32 [4096][512] -> out bf16. One wave per row.
// ---------------------------------------------------------------------------
__global__ __launch_bounds__(256) void ln_k(const float* __restrict__ x,
                                            const float* __restrict__ sc,
                                            const float* __restrict__ bi,
                                            bf16* __restrict__ out) {
  const int w = threadIdx.x >> 6, l = threadIdx.x & 63;
  const int row = blockIdx.x * 4 + w;
  const float4* xp = (const float4*)(x + (size_t)row * 512 + l * 8);
  float4 v0 = xp[0], v1 = xp[1];
  float xv[8] = {v0.x, v0.y, v0.z, v0.w, v1.x, v1.y, v1.z, v1.w};
  float s = 0.f, q = 0.f;
#pragma unroll
  for (int j = 0; j < 8; ++j) { s += xv[j]; q += xv[j] * xv[j]; }
#pragma unroll
  for (int m = 1; m < 64; m <<= 1) { s += __shfl_xor(s, m); q += __shfl_xor(q, m); }
  const float mean = s * (1.f / 512.f);
  const float var = q * (1.f / 512.f) - mean * mean;
  const float rstd = rsqrtf(var + 1e-6f);
  const float4* scp = (const float4*)(sc + l * 8);
  const float4* bip = (const float4*)(bi + l * 8);
  float4 s0 = scp[0], s1 = scp[1], b0 = bip[0], b1 = bip[1];
  float sv[8] = {s0.x, s0.y, s0.z, s0.w, s1.x, s1.y, s1.z, s1.w};
  float bv[8] = {b0.x, b0.y, b0.z, b0.w, b1.x, b1.y, b1.z, b1.w};
  bf16x8 ov;
#pragma unroll
  for (int j = 0; j < 8; ++j) ov[j] = (bf16)((xv[j] - mean) * rstd * sv[j] + bv[j]);
  *(bf16x8*)(out + (size_t)row * 512 + l * 8) = ov;
}

// ---------------------------------------------------------------------------
// Combine 2 split-K partials + bias + residual, then LayerNorm.
// x2 = p0+p1+bo+x  (fp32 out), h2 = LN(x2) (bf16 out)
// ---------------------------------------------------------------------------
__global__ __launch_bounds__(256) void ln2_comb(const float* __restrict__ p0,
                                                const float* __restrict__ p1,
                                                const float* __restrict__ x,
                                                const float* __restrict__ bo,
                                                const float* __restrict__ sc,
                                                const float* __restrict__ bi,
                                                float* __restrict__ x2,
                                                bf16* __restrict__ h2) {
  const int w = threadIdx.x >> 6, l = threadIdx.x & 63;
  const int row = blockIdx.x * 4 + w;
  const size_t base = (size_t)row * 512 + l * 8;
  float xv[8];
#pragma unroll
  for (int j = 0; j < 2; ++j) {
    float4 a = *(const float4*)(p0 + base + j * 4);
    float4 b = *(const float4*)(p1 + base + j * 4);
    float4 c = *(const float4*)(x + base + j * 4);
    float4 d = *(const float4*)(bo + l * 8 + j * 4);
    xv[j * 4 + 0] = a.x + b.x + c.x + d.x;
    xv[j * 4 + 1] = a.y + b.y + c.y + d.y;
    xv[j * 4 + 2] = a.z + b.z + c.z + d.z;
    xv[j * 4 + 3] = a.w + b.w + c.w + d.w;
  }
  *(float4*)(x2 + base) = make_float4(xv[0], xv[1], xv[2], xv[3]);
  *(float4*)(x2 + base + 4) = make_float4(xv[4], xv[5], xv[6], xv[7]);
  float s = 0.f, q = 0.f;
#pragma unroll
  for (int j = 0; j < 8; ++j) { s += xv[j]; q += xv[j] * xv[j]; }
#pragma unroll
  for (int m = 1; m < 64; m <<= 1) { s += __shfl_xor(s, m); q += __shfl_xor(q, m); }
  const float mean = s * (1.f / 512.f);
  const float var = q * (1.f / 512.f) - mean * mean;
  const float rstd = rsqrtf(var + 1e-6f);
  const float4* scp = (const float4*)(sc + l * 8);
  const float4* bip = (const float4*)(bi + l * 8);
  float4 s0 = scp[0], s1 = scp[1], b0 = bip[0], b1 = bip[1];
  float sv[8] = {s0.x, s0.y, s0.z, s0.w, s1.x, s1.y, s1.z, s1.w};
  float bv[8] = {b0.x, b0.y, b0.z, b0.w, b1.x, b1.y, b1.z, b1.w};
  bf16x8 ov;
#pragma unroll
  for (int j = 0; j < 8; ++j) ov[j] = (bf16)((xv[j] - mean) * rstd * sv[j] + bv[j]);
  *(bf16x8*)(h2 + base) = ov;
}

// out = sum(parts[0..nsplit)) + b2 + x2   (all fp32)
__global__ __launch_bounds__(256) void final_comb(const float* __restrict__ parts, int nsplit,
                                                  const float* __restrict__ b2,
                                                  const float* __restrict__ x2,
                                                  float* __restrict__ outp) {
  const int i4 = blockIdx.x * 256 + threadIdx.x;  // f32x4 index, 524288 total
  const size_t off = (size_t)i4 * 4;
  float4 acc = *(const float4*)(x2 + off);
  float4 bb = *(const float4*)(b2 + (off & 511));
  acc.x += bb.x; acc.y += bb.y; acc.z += bb.z; acc.w += bb.w;
  for (int z = 0; z < nsplit; ++z) {
    float4 p = *(const float4*)(parts + (size_t)z * 4096 * 512 + off);
    acc.x += p.x; acc.y += p.y; acc.z += p.z; acc.w += p.w;
  }
  *(float4*)(outp + off) = acc;
}

// ---------------------------------------------------------------------------
// GEMM: C[M][N] = A[M][K] @ Bt[N][K]^T + bias (epilogues as before)
// ---------------------------------------------------------------------------
template <int EPI>
__global__ __launch_bounds__(256) void gemm_bt(const bf16* __restrict__ A,
                                               const bf16* __restrict__ Bt,
                                               const float* __restrict__ bias,
                                               const float* __restrict__ res,
                                               void* __restrict__ outp,
                                               int M, int N, int K) {
  __shared__ bf16 a_lds[128 * 32];
  __shared__ bf16 b_lds[128 * 32];
  const int m0 = blockIdx.x * 128, n0 = blockIdx.y * 128;
  const int tid = threadIdx.x, l = tid & 63, w = tid >> 6;
  const int wm = w >> 1, wn = w & 1;
  const int lc = l & 15, g = l >> 4;

  f32x4 acc[4][4] = {};

  const int kiters = K >> 5;
  for (int kt = 0; kt < kiters; ++kt) {
    const int k0 = kt << 5;
#pragma unroll
    for (int r = 0; r < 2; ++r) {
      const int row = r * 64 + w * 16 + (l >> 2);
      const int c8 = (l & 3) * 8;
      gload_lds16(A + (size_t)(m0 + row) * K + k0 + c8,
                  (char*)a_lds + (r * 64 + w * 16) * 64);
      gload_lds16(Bt + (size_t)(n0 + row) * K + k0 + c8,
                  (char*)b_lds + (r * 64 + w * 16) * 64);
    }
    __syncthreads();

    bf16x8 af[4], bfr[4];
#pragma unroll
    for (int i = 0; i < 4; ++i) {
      af[i]  = *(const bf16x8*)(a_lds + (wm * 64 + i * 16 + lc) * 32 + g * 8);
      bfr[i] = *(const bf16x8*)(b_lds + (wn * 64 + i * 16 + lc) * 32 + g * 8);
    }
#pragma unroll
    for (int mi = 0; mi < 4; ++mi)
#pragma unroll
      for (int ni = 0; ni < 4; ++ni)
        acc[mi][ni] = MFMA16(af[mi], bfr[ni], acc[mi][ni]);
    __syncthreads();
  }

#pragma unroll
  for (int mi = 0; mi < 4; ++mi)
#pragma unroll
    for (int ni = 0; ni < 4; ++ni) {
      const int col = n0 + wn * 64 + ni * 16 + lc;
      const float bb = bias[col];
#pragma unroll
      for (int i = 0; i < 4; ++i) {
        const int row = m0 + wm * 64 + mi * 16 + g * 4 + i;
        float v = acc[mi][ni][i] + bb;
        if constexpr (EPI == 0) {
          ((bf16*)outp)[(size_t)row * N + col] = (bf16)v;
        } else if constexpr (EPI == 1) {
          ((float*)outp)[(size_t)row * N + col] = v + res[(size_t)row * N + col];
        } else {
          float t = 0.7978845608028654f * (v + 0.044715f * v * v * v);
          float gl = 0.5f * v * (1.f + tanhf(t));
          ((bf16*)outp)[(size_t)row * N + col] = (bf16)gl;
        }
      }
    }
}

// ---------------------------------------------------------------------------
// Split-K GEMM partial: parts[kz][M][N] = A[:, kz*Kc:(kz+1)*Kc] @ Bt^T (raw f32)
// ---------------------------------------------------------------------------
__global__ __launch_bounds__(256) void gemm_skp(const bf16* __restrict__ A,
                                                const bf16* __restrict__ Bt,
                                                float* __restrict__ parts,
                                                int M, int N, int Kstride, int Kc) {
  __shared__ bf16 a_lds[128 * 32];
  __shared__ bf16 b_lds[128 * 32];
  const int m0 = blockIdx.x * 128, n0 = blockIdx.y * 128, kz = blockIdx.z;
  A += (size_t)kz * Kc;
  Bt += (size_t)kz * Kc;
  float* outp = parts + (size_t)kz * M * N;
  const int tid = threadIdx.x, l = tid & 63, w = tid >> 6;
  const int wm = w >> 1, wn = w & 1;
  const int lc = l & 15, g = l >> 4;

  f32x4 acc[4][4] = {};

  const int kiters = Kc >> 5;
  for (int kt = 0; kt < kiters; ++kt) {
    const int k0 = kt << 5;
#pragma unroll
    for (int r = 0; r < 2; ++r) {
      const int row = r * 64 + w * 16 + (l >> 2);
      const int c8 = (l & 3) * 8;
      gload_lds16(A + (size_t)(m0 + row) * Kstride + k0 + c8,
                  (char*)a_lds + (r * 64 + w * 16) * 64);
      gload_lds16(Bt + (size_t)(n0 + row) * Kstride + k0 + c8,
                  (char*)b_lds + (r * 64 + w * 16) * 64);
    }
    __syncthreads();

    bf16x8 af[4], bfr[4];
#pragma unroll
    for (int i = 0; i < 4; ++i) {
      af[i]  = *(const bf16x8*)(a_lds + (wm * 64 + i * 16 + lc) * 32 + g * 8);
      bfr[i] = *(const bf16x8*)(b_lds + (wn * 64 + i * 16 + lc) * 32 + g * 8);
    }
#pragma unroll
    for (int mi = 0; mi < 4; ++mi)
#pragma unroll
      for (int ni = 0; ni < 4; ++ni)
        acc[mi][ni] = MFMA16(af[mi], bfr[ni], acc[mi][ni]);
    __syncthreads();
  }

#pragma unroll
  for (int mi = 0; mi < 4; ++mi)
#pragma unroll
    for (int ni = 0; ni < 4; ++ni) {
      const int col = n0 + wn * 64 + ni * 16 + lc;
#pragma unroll
      for (int i = 0; i < 4; ++i) {
        const int row = m0 + wm * 64 + mi * 16 + g * 4 + i;
        outp[(size_t)row * N + col] = acc[mi][ni][i];
      }
    }
}

// ---------------------------------------------------------------------------
// V transpose: qkv[t][1024 + h*64 + d] -> vt[h][d][t]   (bf16)
// ---------------------------------------------------------------------------
__global__ __launch_bounds__(256) void vtrans(const bf16* __restrict__ qkv,
                                              bf16* __restrict__ vt) {
  __shared__ bf16 tile[64][72];
  const int t0 = blockIdx.x * 64;
  const int head = blockIdx.y;
  const int tid = threadIdx.x;
#pragma unroll
  for (int s = 0; s < 16; ++s) {
    int j = tid + s * 256;
    int t = j >> 6, c = j & 63;
    tile[t][c] = qkv[(size_t)(t0 + t) * 1536 + 1024 + head * 64 + c];
  }
  __syncthreads();
#pragma unroll
  for (int s = 0; s < 16; ++s) {
    int j = tid + s * 256;
    int d = j >> 6, t = j & 63;
    vt[(size_t)head * 64 * 4096 + (size_t)d * 4096 + t0 + t] = tile[t][d];
  }
}

// ---------------------------------------------------------------------------
// Flash attention v3: 32x32x16 MFMA, swapped operands, in-register softmax.
// Block = (head, 64 q-rows). 4 waves: wave w -> q-half (w&1), key-half (w>>1).
// Per wave: 32 q rows, 2048 keys in 32 tiles of 64.
//  QK^T: S^T = mfma(A=K rows, B=Q rows): lane(q=l&31,hi=l>>5) holds
//        S[q][key=crow(r,hi)] per 32-key tile, crow=(r&3)+8*(r>>2)+4*hi.
//  Softmax: P = exp2(S/8*log2e) (constant shift cancels in O/l -> exact);
//        psum accumulated per-lane, combined once at the end.
//  P->bf16 fragments: packed casts + v_permlane32_swap_b32 (one swap fills
//        two words: new_X={X_lo,Y_lo}, new_Y={X_hi,Y_hi}).
//  PV: O^T = mfma(A=Vt rows d, B=P rows q) -> lane holds O[q=l&31][16 d's].
//  End: wave-pair partials combined via LDS; l = psum + shfl_xor(psum,32).
// K/V tiles LDS-staged per pair, double-buffered, source-side XOR swizzle.
// ---------------------------------------------------------------------------
__global__ __launch_bounds__(256) void attn_k(const bf16* __restrict__ qkv,
                                              const bf16* __restrict__ vt,
                                              bf16* __restrict__ out) {
  const int bid = blockIdx.x;
  const int head = bid & 7;      // one head per XCD (L2 locality)
  const int qt = bid >> 3;
  const int w = threadIdx.x >> 6, l = threadIdx.x & 63;
  const int hi = l >> 5, l5 = l & 31;
  const int pair = w >> 1, wq = w & 1;

  __shared__ bf16 kbuf[2][2][64 * 64];   // [pair][dbuf]
  __shared__ bf16 vbuf[2][2][64 * 64];

  const int srow = l >> 3;           // staging row within 8-row group
  const int cs = (l & 7) ^ srow;     // pre-swizzled source 16B-chunk

  const bf16* kg = qkv + 512 + head * 64;          // K rows, stride 1536
  const bf16* vg = vt + (size_t)head * 64 * 4096;  // Vt rows (d), stride 4096

  // Q fragments: qf[cc] = Q[q=l5][cc*16 + hi*8 + 0..7]
  const int qrow0 = qt * 64 + wq * 32;
  const bf16* qb = qkv + (size_t)(qrow0 + l5) * 1536 + head * 64;
  bf16x8 qf[4];
#pragma unroll
  for (int cc = 0; cc < 4; ++cc) qf[cc] = *(const bf16x8*)(qb + cc * 16 + hi * 8);

  const int kbase = pair * 2048;   // this wave-pair's first key

  // prologue: stage key-tile 0 into buf 0 (each wave stages 32 K + 32 V rows)
#pragma unroll
  for (int j = 0; j < 4; ++j) {
    const int rr = wq * 32 + j * 8;
    gload_lds16(kg + (size_t)(kbase + rr + srow) * 1536 + cs * 8,
                (char*)kbuf[pair][0] + rr * 128);
    gload_lds16(vg + (size_t)(rr + srow) * 4096 + kbase + cs * 8,
                (char*)vbuf[pair][0] + rr * 128);
  }
  __syncthreads();

  f32x16 o0 = {}, o1 = {};
  float psum = 0.f;
  constexpr float C1 = 0.125f * 1.44269504088896f;  // 1/sqrt(64) * log2(e)
  const int swl = l5 & 7;

  for (int kt = 0; kt < 32; ++kt) {
    const int cur = kt & 1;
    if (kt < 31) {
      const int kv0 = kbase + (kt + 1) * 64;
#pragma unroll
      for (int j = 0; j < 4; ++j) {
        const int rr = wq * 32 + j * 8;
        gload_lds16(kg + (size_t)(kv0 + rr + srow) * 1536 + cs * 8,
                    (char*)kbuf[pair][cur ^ 1] + rr * 128);
        gload_lds16(vg + (size_t)(rr + srow) * 4096 + kv0 + cs * 8,
                    (char*)vbuf[pair][cur ^ 1] + rr * 128);
      }
    }
    const bf16* kb = kbuf[pair][cur];
    const bf16* vb = vbuf[pair][cur];

    // QK^T: two 32-key tiles
    f32x16 s0 = {}, s1 = {};
#pragma unroll
    for (int cc = 0; cc < 4; ++cc) {
      const int sw = ((cc * 2 + hi) ^ swl) * 8;
      bf16x8 kf0 = *(const bf16x8*)(kb + l5 * 64 + sw);
      bf16x8 kf1 = *(const bf16x8*)(kb + (32 + l5) * 64 + sw);
      s0 = MFMA32(kf0, qf[cc], s0);
      s1 = MFMA32(kf1, qf[cc], s1);
    }

    // per 16-key chunk: exp -> pack -> permlane-swap -> PV mfma
#pragma unroll
    for (int c = 0; c < 4; ++c) {
      const int a = (c & 1) * 8;
      float p[8];
#pragma unroll
      for (int j = 0; j < 8; ++j) {
        const float sv = (c < 2) ? ((const f32x16&)s0)[a + j] : ((const f32x16&)s1)[a + j];
        p[j] = exp2f(sv * C1);
        psum += p[j];
      }
      unsigned X = pk2(p[0], p[1]), X2 = pk2(p[2], p[3]);
      unsigned Y = pk2(p[4], p[5]), Y2 = pk2(p[6], p[7]);
      asm volatile("v_permlane32_swap_b32 %0, %1" : "+v"(X), "+v"(Y));
      asm volatile("v_permlane32_swap_b32 %0, %1" : "+v"(X2), "+v"(Y2));
      union { unsigned wd[4]; bf16x8 v; } pa;
      pa.wd[0] = X; pa.wd[1] = X2; pa.wd[2] = Y; pa.wd[3] = Y2;
      const int sw = ((c * 2 + hi) ^ swl) * 8;
      bf16x8 vf0 = *(const bf16x8*)(vb + l5 * 64 + sw);
      bf16x8 vf1 = *(const bf16x8*)(vb + (32 + l5) * 64 + sw);
      o0 = MFMA32(vf0, pa.v, o0);
      o1 = MFMA32(vf1, pa.v, o1);
    }
    __syncthreads();
  }

  // combine wave-pair key-half partials via LDS (overlay on kbuf, now dead)
  float* comb = (float*)&kbuf[0][0][0];   // 2*64*33 f32 = 16.9 KB
  if (w >= 2) {
    float* cb = comb + ((w - 2) * 64 + l) * 33;
#pragma unroll
    for (int r = 0; r < 16; ++r) { cb[r] = o0[r]; cb[16 + r] = o1[r]; }
    cb[32] = psum;
  }
  __syncthreads();
  if (w < 2) {
    const float* cb = comb + (w * 64 + l) * 33;
#pragma unroll
    for (int r = 0; r < 16; ++r) { o0[r] += cb[r]; o1[r] += cb[16 + r]; }
    psum += cb[32];
    const float lsum = psum + __shfl_xor(psum, 32);
    const float inv = 1.f / lsum;
    bf16* ob = out + (size_t)(qrow0 + l5) * 512 + head * 64;
#pragma unroll
    for (int dt = 0; dt < 2; ++dt)
#pragma unroll
      for (int rg = 0; rg < 4; ++rg) {
        bf16x4 vv;
#pragma unroll
        for (int e = 0; e < 4; ++e) {
          const float ov = (dt == 0) ? o0[rg * 4 + e] : o1[rg * 4 + e];
          vv[e] = (bf16)(ov * inv);
        }
        *(bf16x4*)(ob + dt * 32 + rg * 8 + hi * 4) = vv;
      }
  }
}

// ---------------------------------------------------------------------------
extern "C" void kernel_launch(void* const* d_in, const int* in_sizes, int n_in,
                              void* d_out, int out_size, void* d_ws, size_t ws_size,
                              hipStream_t stream) {
  const float* x    = (const float*)d_in[0];
  const float* ln1s = (const float*)d_in[1];
  const float* ln1b = (const float*)d_in[2];
  const float* Wq   = (const float*)d_in[3];
  const float* bq   = (const float*)d_in[4];
  const float* Wk   = (const float*)d_in[5];
  const float* bk   = (const float*)d_in[6];
  const float* Wv   = (const float*)d_in[7];
  const float* bv   = (const float*)d_in[8];
  const float* Wo   = (const float*)d_in[9];
  const float* bo   = (const float*)d_in[10];
  const float* ln2s = (const float*)d_in[11];
  const float* ln2b = (const float*)d_in[12];
  const float* W1   = (const float*)d_in[13];
  const float* b1   = (const float*)d_in[14];
  const float* W2   = (const float*)d_in[15];
  const float* b2   = (const float*)d_in[16];
  float* out = (float*)d_out;

  char* ws = (char*)d_ws;
  bf16* wqkvT = (bf16*)(ws + 0);               // [1536][512]   1.5 MB
  bf16* woT   = (bf16*)(ws + 1572864);         // [512][512]    0.5 MB
  bf16* w1T   = (bf16*)(ws + 2097152);         // [2048][512]   2 MB
  bf16* w2T   = (bf16*)(ws + 4194304);         // [512][2048]   2 MB
  float* bqkv = (float*)(ws + 6291456);        // [1536]
  float* x2   = (float*)(ws + 6299648);        // [4096][512] fp32  8 MB
  bf16* h     = (bf16*)(ws + 14688256);        // [4096][512]   4 MB (reused as h2)
  bf16* qkv   = (bf16*)(ws + 18882560);        // [4096][1536] 12 MB
  bf16* vt    = (bf16*)(ws + 31465472);        // [8][64][4096] 4 MB
  bf16* attnb = (bf16*)(ws + 35659776);        // [4096][512]   4 MB   (end 39854080)
  bf16* h2   = h;
  bf16* gbuf = qkv;                            // [4096][2048] 16 MB (qkv+vt dead)
  // wo split-K partials (2 x 8 MB f32) overlay the dead qkv+vt region
  float* wop = (float*)(ws + 18882560);
  // ffn2 partials live past the proven region — gated on ws_size
  float* f2p = (float*)(ws + 39854080);
  const size_t need4 = 39854080 + 4ull * 8388608;
  const size_t need2 = 39854080 + 2ull * 8388608;

  // weight prep
  wtrans<<<dim3(8, 8),  256, 0, stream>>>(Wq, wqkvT,               512, 512);
  wtrans<<<dim3(8, 8),  256, 0, stream>>>(Wk, wqkvT + 512 * 512,   512, 512);
  wtrans<<<dim3(8, 8),  256, 0, stream>>>(Wv, wqkvT + 1024 * 512,  512, 512);
  wtrans<<<dim3(8, 8),  256, 0, stream>>>(Wo, woT,                 512, 512);
  wtrans<<<dim3(8, 32), 256, 0, stream>>>(W1, w1T,                 512, 2048);
  wtrans<<<dim3(32, 8), 256, 0, stream>>>(W2, w2T,                 2048, 512);
  packbias<<<6, 256, 0, stream>>>(bq, bk, bv, bqkv);

  // block
  ln_k<<<1024, 256, 0, stream>>>(x, ln1s, ln1b, h);
  gemm_bt<0><<<dim3(32, 12), 256, 0, stream>>>(h, wqkvT, bqkv, nullptr, qkv, 4096, 1536, 512);
  vtrans<<<dim3(64, 8), 256, 0, stream>>>(qkv, vt);
  attn_k<<<512, 256, 0, stream>>>(qkv, vt, attnb);
  // attn-out projection: split-K=2, partials in dead qkv/vt space
  gemm_skp<<<dim3(32, 4, 2), 256, 0, stream>>>(attnb, woT, wop, 4096, 512, 512, 256);
  ln2_comb<<<1024, 256, 0, stream>>>(wop, wop + 4096 * 512, x, bo, ln2s, ln2b, x2, h2);
  gemm_bt<2><<<dim3(32, 16), 256, 0, stream>>>(h2, w1T, b1, nullptr, gbuf, 4096, 2048, 512);
  if (ws_size >= need4) {
    gemm_skp<<<dim3(32, 4, 4), 256, 0, stream>>>(gbuf, w2T, f2p, 4096, 512, 2048, 512);
    final_comb<<<2048, 256, 0, stream>>>(f2p, 4, b2, x2, out);
  } else if (ws_size >= need2) {
    gemm_skp<<<dim3(32, 4, 2), 256, 0, stream>>>(gbuf, w2T, f2p, 4096, 512, 2048, 1024);
    final_comb<<<2048, 256, 0, stream>>>(f2p, 2, b2, x2, out);
  } else {
    gemm_bt<1><<<dim3(32, 4), 256, 0, stream>>>(gbuf, w2T, b2, x2, out, 4096, 512, 2048);
  }
}

// Round 4
// 161.950 us; speedup vs baseline: 2.4919x; 1.2174x over previous
//
#include <hip/hip_runtime.h>
#include <hip/hip_bf16.h>
#include <stdint.h>

typedef __bf16 bf16;
typedef __bf16 bf16x4 __attribute__((ext_vector_type(4)));
typedef __bf16 bf16x8 __attribute__((ext_vector_type(8)));
typedef float  f32x4  __attribute__((ext_vector_type(4)));
typedef float  f32x16 __attribute__((ext_vector_type(16)));

#define MFMA16(A_, B_, C_) __builtin_amdgcn_mfma_f32_16x16x32_bf16((A_), (B_), (C_), 0, 0, 0)
#define MFMA32(A_, B_, C_) __builtin_amdgcn_mfma_f32_32x32x16_bf16((A_), (B_), (C_), 0, 0, 0)

#define QSCALE 0.1803368801111137f  // 0.125 * log2(e), folded into Wq/bq

__device__ __forceinline__ void gload_lds16(const void* g, void* l) {
  __builtin_amdgcn_global_load_lds(
      (const __attribute__((address_space(1))) unsigned int*)g,
      (__attribute__((address_space(3))) unsigned int*)l, 16, 0, 0);
}

__device__ __forceinline__ unsigned pk2(float lo, float hi_) {
  union { bf16 h[2]; unsigned u; } t;
  t.h[0] = (bf16)lo; t.h[1] = (bf16)hi_;
  return t.u;
}

// ---------------------------------------------------------------------------
// prep: all weight transposes (fp32->bf16, out[n][k]=in[k][n]*scale) + bias pack
// blocks 0..63 Wq(x QSCALE) | 64..127 Wk | 128..191 Wv | 192..255 Wo |
// 256..511 W1 | 512..767 W2 | 768..773 bias pack (bq x QSCALE)
// ---------------------------------------------------------------------------
__global__ __launch_bounds__(256) void prep(const float* __restrict__ Wq,
                                            const float* __restrict__ Wk,
                                            const float* __restrict__ Wv,
                                            const float* __restrict__ Wo,
                                            const float* __restrict__ W1,
                                            const float* __restrict__ W2,
                                            const float* __restrict__ bq,
                                            const float* __restrict__ bk,
                                            const float* __restrict__ bv,
                                            bf16* __restrict__ wqkvT, bf16* __restrict__ woT,
                                            bf16* __restrict__ w1T, bf16* __restrict__ w2T,
                                            float* __restrict__ bqkv) {
  const int b = blockIdx.x;
  if (b >= 768) {
    int i = (b - 768) * 256 + threadIdx.x;
    if (i < 1536)
      bqkv[i] = (i < 512) ? bq[i] * QSCALE : (i < 1024 ? bk[i - 512] : bv[i - 1024]);
    return;
  }
  const float* in; bf16* outp; int K, N, t; float sc = 1.f;
  if (b < 64)       { in = Wq; outp = wqkvT;              K = 512;  N = 512;  t = b;       sc = QSCALE; }
  else if (b < 128) { in = Wk; outp = wqkvT + 512 * 512;  K = 512;  N = 512;  t = b - 64;  }
  else if (b < 192) { in = Wv; outp = wqkvT + 1024 * 512; K = 512;  N = 512;  t = b - 128; }
  else if (b < 256) { in = Wo; outp = woT;                K = 512;  N = 512;  t = b - 192; }
  else if (b < 512) { in = W1; outp = w1T;                K = 512;  N = 2048; t = b - 256; }
  else              { in = W2; outp = w2T;                K = 2048; N = 512;  t = b - 512; }
  const int tx = K >> 6;
  const int k0 = (t % tx) * 64, n0 = (t / tx) * 64;
  __shared__ bf16 tile[64][72];
  const int tid = threadIdx.x;
#pragma unroll
  for (int s = 0; s < 16; ++s) {
    int j = tid + s * 256;
    int r = j >> 6, c = j & 63;
    tile[r][c] = (bf16)(in[(size_t)(k0 + r) * N + n0 + c] * sc);
  }
  __syncthreads();
#pragma unroll
  for (int s = 0; s < 16; ++s) {
    int j = tid + s * 256;
    int n = j >> 6, k = j & 63;
    outp[(size_t)(n0 + n) * K + k0 + k] = tile[k][n];
  }
}

// ---------------------------------------------------------------------------
// LayerNorm: x fp32 [4096][512] -> out bf16. One wave per row.
// ---------------------------------------------------------------------------
__global__ __launch_bounds__(256) void ln_k(const float* __restrict__ x,
                                            const float* __restrict__ sc,
                                            const float* __restrict__ bi,
                                            bf16* __restrict__ out) {
  const int w = threadIdx.x >> 6, l = threadIdx.x & 63;
  const int row = blockIdx.x * 4 + w;
  const float4* xp = (const float4*)(x + (size_t)row * 512 + l * 8);
  float4 v0 = xp[0], v1 = xp[1];
  float xv[8] = {v0.x, v0.y, v0.z, v0.w, v1.x, v1.y, v1.z, v1.w};
  float s = 0.f, q = 0.f;
#pragma unroll
  for (int j = 0; j < 8; ++j) { s += xv[j]; q += xv[j] * xv[j]; }
#pragma unroll
  for (int m = 1; m < 64; m <<= 1) { s += __shfl_xor(s, m); q += __shfl_xor(q, m); }
  const float mean = s * (1.f / 512.f);
  const float var = q * (1.f / 512.f) - mean * mean;
  const float rstd = rsqrtf(var + 1e-6f);
  const float4* scp = (const float4*)(sc + l * 8);
  const float4* bip = (const float4*)(bi + l * 8);
  float4 s0 = scp[0], s1 = scp[1], b0 = bip[0], b1 = bip[1];
  float sv[8] = {s0.x, s0.y, s0.z, s0.w, s1.x, s1.y, s1.z, s1.w};
  float bv[8] = {b0.x, b0.y, b0.z, b0.w, b1.x, b1.y, b1.z, b1.w};
  bf16x8 ov;
#pragma unroll
  for (int j = 0; j < 8; ++j) ov[j] = (bf16)((xv[j] - mean) * rstd * sv[j] + bv[j]);
  *(bf16x8*)(out + (size_t)row * 512 + l * 8) = ov;
}

// ---------------------------------------------------------------------------
// ln2_comb: x2 = p0+p1+bo+x (fp32), h2 = LN(x2) (bf16)
// ---------------------------------------------------------------------------
__global__ __launch_bounds__(256) void ln2_comb(const float* __restrict__ p0,
                                                const float* __restrict__ p1,
                                                const float* __restrict__ x,
                                                const float* __restrict__ bo,
                                                const float* __restrict__ sc,
                                                const float* __restrict__ bi,
                                                float* __restrict__ x2,
                                                bf16* __restrict__ h2) {
  const int w = threadIdx.x >> 6, l = threadIdx.x & 63;
  const int row = blockIdx.x * 4 + w;
  const size_t base = (size_t)row * 512 + l * 8;
  float xv[8];
#pragma unroll
  for (int j = 0; j < 2; ++j) {
    float4 a = *(const float4*)(p0 + base + j * 4);
    float4 b = *(const float4*)(p1 + base + j * 4);
    float4 c = *(const float4*)(x + base + j * 4);
    float4 d = *(const float4*)(bo + l * 8 + j * 4);
    xv[j * 4 + 0] = a.x + b.x + c.x + d.x;
    xv[j * 4 + 1] = a.y + b.y + c.y + d.y;
    xv[j * 4 + 2] = a.z + b.z + c.z + d.z;
    xv[j * 4 + 3] = a.w + b.w + c.w + d.w;
  }
  *(float4*)(x2 + base) = make_float4(xv[0], xv[1], xv[2], xv[3]);
  *(float4*)(x2 + base + 4) = make_float4(xv[4], xv[5], xv[6], xv[7]);
  float s = 0.f, q = 0.f;
#pragma unroll
  for (int j = 0; j < 8; ++j) { s += xv[j]; q += xv[j] * xv[j]; }
#pragma unroll
  for (int m = 1; m < 64; m <<= 1) { s += __shfl_xor(s, m); q += __shfl_xor(q, m); }
  const float mean = s * (1.f / 512.f);
  const float var = q * (1.f / 512.f) - mean * mean;
  const float rstd = rsqrtf(var + 1e-6f);
  const float4* scp = (const float4*)(sc + l * 8);
  const float4* bip = (const float4*)(bi + l * 8);
  float4 s0 = scp[0], s1 = scp[1], b0 = bip[0], b1 = bip[1];
  float sv[8] = {s0.x, s0.y, s0.z, s0.w, s1.x, s1.y, s1.z, s1.w};
  float bv[8] = {b0.x, b0.y, b0.z, b0.w, b1.x, b1.y, b1.z, b1.w};
  bf16x8 ov;
#pragma unroll
  for (int j = 0; j < 8; ++j) ov[j] = (bf16)((xv[j] - mean) * rstd * sv[j] + bv[j]);
  *(bf16x8*)(h2 + base) = ov;
}

// out = sum(parts) + b2 + x2   (all fp32)
__global__ __launch_bounds__(256) void final_comb(const float* __restrict__ parts, int nsplit,
                                                  const float* __restrict__ b2,
                                                  const float* __restrict__ x2,
                                                  float* __restrict__ outp) {
  const int i4 = blockIdx.x * 256 + threadIdx.x;
  const size_t off = (size_t)i4 * 4;
  float4 acc = *(const float4*)(x2 + off);
  float4 bb = *(const float4*)(b2 + (off & 511));
  acc.x += bb.x; acc.y += bb.y; acc.z += bb.z; acc.w += bb.w;
  for (int z = 0; z < nsplit; ++z) {
    float4 p = *(const float4*)(parts + (size_t)z * 4096 * 512 + off);
    acc.x += p.x; acc.y += p.y; acc.z += p.z; acc.w += p.w;
  }
  *(float4*)(outp + off) = acc;
}

// ---------------------------------------------------------------------------
// GEMM core, BK=64, XOR-swizzled LDS (phys_chunk = logical ^ (row&7)).
// C[M][N] = A[M][K] @ Bt[N][K]^T. EPI 0: +bias->bf16, 1: +bias+res->f32,
// 2: +bias,gelu->bf16
// ---------------------------------------------------------------------------
template <int EPI>
__global__ __launch_bounds__(256) void gemm_bt(const bf16* __restrict__ A,
                                               const bf16* __restrict__ Bt,
                                               const float* __restrict__ bias,
                                               const float* __restrict__ res,
                                               void* __restrict__ outp,
                                               int M, int N, int K) {
  __shared__ bf16 a_lds[128 * 64];
  __shared__ bf16 b_lds[128 * 64];
  const int m0 = blockIdx.x * 128, n0 = blockIdx.y * 128;
  const int tid = threadIdx.x, l = tid & 63, w = tid >> 6;
  const int wm = w >> 1, wn = w & 1;
  const int lc = l & 15, g = l >> 4;
  const int srow = l >> 3;
  const int cs = (l & 7) ^ srow;

  f32x4 acc[4][4] = {};
  const int kiters = K >> 6;
  for (int kt = 0; kt < kiters; ++kt) {
    const int k0 = kt << 6;
#pragma unroll
    for (int r = 0; r < 4; ++r) {
      const int rg = r * 32 + w * 8;
      gload_lds16(A + (size_t)(m0 + rg + srow) * K + k0 + cs * 8,
                  (char*)a_lds + rg * 128);
      gload_lds16(Bt + (size_t)(n0 + rg + srow) * K + k0 + cs * 8,
                  (char*)b_lds + rg * 128);
    }
    __syncthreads();
#pragma unroll
    for (int kk = 0; kk < 2; ++kk) {
      bf16x8 af[4], bfr[4];
#pragma unroll
      for (int i = 0; i < 4; ++i) {
        const int sw = ((kk * 4 + g) ^ (lc & 7)) * 8;
        af[i]  = *(const bf16x8*)(a_lds + (wm * 64 + i * 16 + lc) * 64 + sw);
        bfr[i] = *(const bf16x8*)(b_lds + (wn * 64 + i * 16 + lc) * 64 + sw);
      }
#pragma unroll
      for (int mi = 0; mi < 4; ++mi)
#pragma unroll
        for (int ni = 0; ni < 4; ++ni)
          acc[mi][ni] = MFMA16(af[mi], bfr[ni], acc[mi][ni]);
    }
    __syncthreads();
  }

#pragma unroll
  for (int mi = 0; mi < 4; ++mi)
#pragma unroll
    for (int ni = 0; ni < 4; ++ni) {
      const int col = n0 + wn * 64 + ni * 16 + lc;
      const float bb = bias[col];
#pragma unroll
      for (int i = 0; i < 4; ++i) {
        const int row = m0 + wm * 64 + mi * 16 + g * 4 + i;
        float v = acc[mi][ni][i] + bb;
        if constexpr (EPI == 0) {
          ((bf16*)outp)[(size_t)row * N + col] = (bf16)v;
        } else if constexpr (EPI == 1) {
          ((float*)outp)[(size_t)row * N + col] = v + res[(size_t)row * N + col];
        } else {
          // gelu(v) = v * sigmoid(2*0.79788456*(v+0.044715 v^3))
          float t = -2.3022077697f * (v + 0.044715f * v * v * v);  // -2k*log2e
          float gl = v / (1.f + exp2f(t));
          ((bf16*)outp)[(size_t)row * N + col] = (bf16)gl;
        }
      }
    }
}

// ---------------------------------------------------------------------------
// Split-K GEMM partial (BK=64, swizzled): parts[kz][M][N] raw f32
// ---------------------------------------------------------------------------
__global__ __launch_bounds__(256) void gemm_skp(const bf16* __restrict__ A,
                                                const bf16* __restrict__ Bt,
                                                float* __restrict__ parts,
                                                int M, int N, int Kstride, int Kc) {
  __shared__ bf16 a_lds[128 * 64];
  __shared__ bf16 b_lds[128 * 64];
  const int m0 = blockIdx.x * 128, n0 = blockIdx.y * 128, kz = blockIdx.z;
  A += (size_t)kz * Kc;
  Bt += (size_t)kz * Kc;
  float* outp = parts + (size_t)kz * M * N;
  const int tid = threadIdx.x, l = tid & 63, w = tid >> 6;
  const int wm = w >> 1, wn = w & 1;
  const int lc = l & 15, g = l >> 4;
  const int srow = l >> 3;
  const int cs = (l & 7) ^ srow;

  f32x4 acc[4][4] = {};
  const int kiters = Kc >> 6;
  for (int kt = 0; kt < kiters; ++kt) {
    const int k0 = kt << 6;
#pragma unroll
    for (int r = 0; r < 4; ++r) {
      const int rg = r * 32 + w * 8;
      gload_lds16(A + (size_t)(m0 + rg + srow) * Kstride + k0 + cs * 8,
                  (char*)a_lds + rg * 128);
      gload_lds16(Bt + (size_t)(n0 + rg + srow) * Kstride + k0 + cs * 8,
                  (char*)b_lds + rg * 128);
    }
    __syncthreads();
#pragma unroll
    for (int kk = 0; kk < 2; ++kk) {
      bf16x8 af[4], bfr[4];
#pragma unroll
      for (int i = 0; i < 4; ++i) {
        const int sw = ((kk * 4 + g) ^ (lc & 7)) * 8;
        af[i]  = *(const bf16x8*)(a_lds + (wm * 64 + i * 16 + lc) * 64 + sw);
        bfr[i] = *(const bf16x8*)(b_lds + (wn * 64 + i * 16 + lc) * 64 + sw);
      }
#pragma unroll
      for (int mi = 0; mi < 4; ++mi)
#pragma unroll
        for (int ni = 0; ni < 4; ++ni)
          acc[mi][ni] = MFMA16(af[mi], bfr[ni], acc[mi][ni]);
    }
    __syncthreads();
  }

#pragma unroll
  for (int mi = 0; mi < 4; ++mi)
#pragma unroll
    for (int ni = 0; ni < 4; ++ni) {
      const int col = n0 + wn * 64 + ni * 16 + lc;
#pragma unroll
      for (int i = 0; i < 4; ++i) {
        const int row = m0 + wm * 64 + mi * 16 + g * 4 + i;
        outp[(size_t)row * N + col] = acc[mi][ni][i];
      }
    }
}

// ---------------------------------------------------------------------------
// V transpose: qkv[t][1024 + h*64 + d] -> vt[h][d][t]   (bf16)
// ---------------------------------------------------------------------------
__global__ __launch_bounds__(256) void vtrans(const bf16* __restrict__ qkv,
                                              bf16* __restrict__ vt) {
  __shared__ bf16 tile[64][72];
  const int t0 = blockIdx.x * 64;
  const int head = blockIdx.y;
  const int tid = threadIdx.x;
#pragma unroll
  for (int s = 0; s < 16; ++s) {
    int j = tid + s * 256;
    int t = j >> 6, c = j & 63;
    tile[t][c] = qkv[(size_t)(t0 + t) * 1536 + 1024 + head * 64 + c];
  }
  __syncthreads();
#pragma unroll
  for (int s = 0; s < 16; ++s) {
    int j = tid + s * 256;
    int d = j >> 6, t = j & 63;
    vt[(size_t)head * 64 * 4096 + (size_t)d * 4096 + t0 + t] = tile[t][d];
  }
}

// ---------------------------------------------------------------------------
// Flash attention v4: 32x32x16 swapped-operand, in-register constant-max
// softmax (scale folded into Wq/bq), KVBLK=32, cross-block key split (ks=2).
// Grid 1024 = head(8) x qt(64) x ks(2). Block: 4 waves, pair=w>>1 gets a
// 1024-key range, wq=w&1 gets a 32-q-row half. LDS 32KB -> 4 blocks/CU.
// Writes RAW O partials (bf16) + l partials (f32); attn_comb divides.
// ---------------------------------------------------------------------------
__global__ __launch_bounds__(256, 4) void attn_k(const bf16* __restrict__ qkv,
                                                 const bf16* __restrict__ vt,
                                                 bf16* __restrict__ opart,
                                                 float* __restrict__ lpart) {
  const int bid = blockIdx.x;
  const int head = bid & 7;          // one head per XCD
  const int qt = (bid >> 3) & 63;
  const int ks = bid >> 9;
  const int w = threadIdx.x >> 6, l = threadIdx.x & 63;
  const int hi = l >> 5, l5 = l & 31;
  const int pair = w >> 1, wq = w & 1;

  __shared__ char smem[32768];
  bf16* kt_l = (bf16*)(smem + pair * 8192);            // [db][32*64]
  bf16* vt_l = (bf16*)(smem + 16384 + pair * 8192);    // [db][64*32]

  const bf16* kg = qkv + 512 + head * 64;              // K rows, stride 1536
  const bf16* vg = vt + (size_t)head * 64 * 4096;      // Vt rows (d), stride 4096

  // Q fragments (Wq pre-scaled by 0.125*log2e)
  const int qrow0 = qt * 64 + wq * 32;
  const bf16* qb = qkv + (size_t)(qrow0 + l5) * 1536 + head * 64;
  bf16x8 qf[4];
#pragma unroll
  for (int cc = 0; cc < 4; ++cc) qf[cc] = *(const bf16x8*)(qb + cc * 16 + hi * 8);

  const int kstart = ks * 2048 + pair * 1024;
  const int srow = l >> 3;
  const int cs_k = (l & 7) ^ srow;            // K swizzle: f(row)=row&7
  const int cs_v = (l & 3) ^ ((l >> 3) & 3);  // V swizzle: f(row)=(row>>1)&3

  // prologue: stage tile 0 into db=0
#pragma unroll
  for (int j = 0; j < 2; ++j) {
    const int rrk = wq * 16 + j * 8;
    gload_lds16(kg + (size_t)(kstart + rrk + srow) * 1536 + cs_k * 8,
                (char*)kt_l + rrk * 128);
    const int rgv = wq * 32 + j * 16;
    gload_lds16(vg + (size_t)(rgv + (l >> 2)) * 4096 + kstart + cs_v * 8,
                (char*)vt_l + rgv * 64);
  }
  __syncthreads();

  f32x16 o0 = {}, o1 = {};
  float psum = 0.f;
  const int swl = l5 & 7, swv = (l5 >> 1) & 3;

  for (int kt = 0; kt < 32; ++kt) {
    const int cur = kt & 1;
    if (kt < 31) {
      const int kv0 = kstart + (kt + 1) * 32;
#pragma unroll
      for (int j = 0; j < 2; ++j) {
        const int rrk = wq * 16 + j * 8;
        gload_lds16(kg + (size_t)(kv0 + rrk + srow) * 1536 + cs_k * 8,
                    (char*)kt_l + (cur ^ 1) * 4096 + rrk * 128);
        const int rgv = wq * 32 + j * 16;
        gload_lds16(vg + (size_t)(rgv + (l >> 2)) * 4096 + kv0 + cs_v * 8,
                    (char*)vt_l + (cur ^ 1) * 4096 + rgv * 64);
      }
    }
    const bf16* kb = kt_l + cur * 2048;
    const bf16* vb = vt_l + cur * 2048;

    // QK^T: S^T[key][q] tile, lane(q=l5,hi) gets 16 keys
    f32x16 s = {};
#pragma unroll
    for (int cc = 0; cc < 4; ++cc) {
      bf16x8 kf = *(const bf16x8*)(kb + l5 * 64 + (((cc * 2 + hi) ^ swl) * 8));
      s = MFMA32(kf, qf[cc], s);
    }

    // softmax + pack + PV per 16-key chunk
#pragma unroll
    for (int c = 0; c < 2; ++c) {
      float p[8];
#pragma unroll
      for (int j = 0; j < 8; ++j) {
        p[j] = exp2f(s[c * 8 + j]);
        psum += p[j];
      }
      unsigned X = pk2(p[0], p[1]), X2 = pk2(p[2], p[3]);
      unsigned Y = pk2(p[4], p[5]), Y2 = pk2(p[6], p[7]);
      asm volatile("v_permlane32_swap_b32 %0, %1" : "+v"(X), "+v"(Y));
      asm volatile("v_permlane32_swap_b32 %0, %1" : "+v"(X2), "+v"(Y2));
      union { unsigned wd[4]; bf16x8 v; } pa;
      pa.wd[0] = X; pa.wd[1] = X2; pa.wd[2] = Y; pa.wd[3] = Y2;
      const int sw = ((c * 2 + hi) ^ swv) * 8;
      bf16x8 vf0 = *(const bf16x8*)(vb + l5 * 32 + sw);
      bf16x8 vf1 = *(const bf16x8*)(vb + (32 + l5) * 32 + sw);
      o0 = MFMA32(vf0, pa.v, o0);
      o1 = MFMA32(vf1, pa.v, o1);
    }
    __syncthreads();
  }

  // combine the two pair (key-range) partials via LDS
  float* comb = (float*)smem;   // 2*64*33*4 = 16896 B, tiles dead
  if (w >= 2) {
    float* cb = comb + ((w - 2) * 64 + l) * 33;
#pragma unroll
    for (int r = 0; r < 16; ++r) { cb[r] = o0[r]; cb[16 + r] = o1[r]; }
    cb[32] = psum;
  }
  __syncthreads();
  if (w < 2) {
    const float* cb = comb + (w * 64 + l) * 33;
#pragma unroll
    for (int r = 0; r < 16; ++r) { o0[r] += cb[r]; o1[r] += cb[16 + r]; }
    psum += cb[32];
    const float lsum = psum + __shfl_xor(psum, 32);
    bf16* ob = opart + (size_t)ks * 4096 * 512 + (size_t)(qrow0 + l5) * 512 + head * 64;
#pragma unroll
    for (int dt = 0; dt < 2; ++dt)
#pragma unroll
      for (int rg = 0; rg < 4; ++rg) {
        bf16x4 vv;
#pragma unroll
        for (int e = 0; e < 4; ++e) {
          const float ov = (dt == 0) ? o0[rg * 4 + e] : o1[rg * 4 + e];
          vv[e] = (bf16)ov;
        }
        *(bf16x4*)(ob + dt * 32 + rg * 8 + hi * 4) = vv;
      }
    if (hi == 0) lpart[(ks * 8 + head) * 4096 + qrow0 + l5] = lsum;
  }
}

// attnb[t][col] = (op0+op1)/(l0+l1)
__global__ __launch_bounds__(256) void attn_comb(const bf16* __restrict__ op,
                                                 const float* __restrict__ lp,
                                                 bf16* __restrict__ ob) {
  const int idx = blockIdx.x * 256 + threadIdx.x;   // 262144 = 4096 * 64
  const int t = idx >> 6, c8 = idx & 63;
  const int head = c8 >> 3;
  const size_t o = (size_t)t * 512 + c8 * 8;
  bf16x8 a = *(const bf16x8*)(op + o);
  bf16x8 b = *(const bf16x8*)(op + 2097152 + o);
  const float inv = 1.f / (lp[head * 4096 + t] + lp[32768 + head * 4096 + t]);
  bf16x8 r;
#pragma unroll
  for (int j = 0; j < 8; ++j) r[j] = (bf16)(((float)a[j] + (float)b[j]) * inv);
  *(bf16x8*)(ob + o) = r;
}

// ---------------------------------------------------------------------------
extern "C" void kernel_launch(void* const* d_in, const int* in_sizes, int n_in,
                              void* d_out, int out_size, void* d_ws, size_t ws_size,
                              hipStream_t stream) {
  const float* x    = (const float*)d_in[0];
  const float* ln1s = (const float*)d_in[1];
  const float* ln1b = (const float*)d_in[2];
  const float* Wq   = (const float*)d_in[3];
  const float* bq   = (const float*)d_in[4];
  const float* Wk   = (const float*)d_in[5];
  const float* bk   = (const float*)d_in[6];
  const float* Wv   = (const float*)d_in[7];
  const float* bv   = (const float*)d_in[8];
  const float* Wo   = (const float*)d_in[9];
  const float* bo   = (const float*)d_in[10];
  const float* ln2s = (const float*)d_in[11];
  const float* ln2b = (const float*)d_in[12];
  const float* W1   = (const float*)d_in[13];
  const float* b1   = (const float*)d_in[14];
  const float* W2   = (const float*)d_in[15];
  const float* b2   = (const float*)d_in[16];
  float* out = (float*)d_out;

  char* ws = (char*)d_ws;
  bf16*  wqkvT = (bf16*)(ws + 0);          // [1536][512] 1.5M
  bf16*  woT   = (bf16*)(ws + 1572864);    // [512][512]  0.5M
  bf16*  w1T   = (bf16*)(ws + 2097152);    // [2048][512] 2M
  bf16*  w2T   = (bf16*)(ws + 4194304);    // [512][2048] 2M
  float* bqkv  = (float*)(ws + 6291456);   // 6144 B
  float* lpart = (float*)(ws + 6297600);   // [2][8][4096] f32 = 256K
  bf16*  opart = (bf16*)(ws + 6559744);    // [2][4096][512] bf16 = 8M (then x2)
  float* x2    = (float*)(ws + 6559744);   //   x2 overlays opart (disjoint life)
  bf16*  h     = (bf16*)(ws + 14948352);   // 4M; shared by h / attnb / h2
  bf16*  qkv   = (bf16*)(ws + 19142656);   // [4096][1536] 12M
  bf16*  vt    = (bf16*)(ws + 31725568);   // [8][64][4096] 4M  (end 35919872)
  bf16*  attnb = h;
  bf16*  h2    = h;
  float* wop   = (float*)(ws + 19142656);  // 2x8M f32 over dead qkv+vt
  bf16*  gbuf  = qkv;                      // ffn1 out 16M over dead wop region
  float* f2p   = (float*)(ws + 35919872);  // gated
  const size_t need4 = 35919872 + 4ull * 8388608;
  const size_t need2 = 35919872 + 2ull * 8388608;

  prep<<<774, 256, 0, stream>>>(Wq, Wk, Wv, Wo, W1, W2, bq, bk, bv,
                                wqkvT, woT, w1T, w2T, bqkv);

  ln_k<<<1024, 256, 0, stream>>>(x, ln1s, ln1b, h);
  gemm_bt<0><<<dim3(32, 12), 256, 0, stream>>>(h, wqkvT, bqkv, nullptr, qkv, 4096, 1536, 512);
  vtrans<<<dim3(64, 8), 256, 0, stream>>>(qkv, vt);
  attn_k<<<1024, 256, 0, stream>>>(qkv, vt, opart, lpart);
  attn_comb<<<1024, 256, 0, stream>>>(opart, lpart, attnb);
  gemm_skp<<<dim3(32, 4, 2), 256, 0, stream>>>(attnb, woT, wop, 4096, 512, 512, 256);
  ln2_comb<<<1024, 256, 0, stream>>>(wop, wop + 4096 * 512, x, bo, ln2s, ln2b, x2, h2);
  gemm_bt<2><<<dim3(32, 16), 256, 0, stream>>>(h2, w1T, b1, nullptr, gbuf, 4096, 2048, 512);
  if (ws_size >= need4) {
    gemm_skp<<<dim3(32, 4, 4), 256, 0, stream>>>(gbuf, w2T, f2p, 4096, 512, 2048, 512);
    final_comb<<<2048, 256, 0, stream>>>(f2p, 4, b2, x2, out);
  } else if (ws_size >= need2) {
    gemm_skp<<<dim3(32, 4, 2), 256, 0, stream>>>(gbuf, w2T, f2p, 4096, 512, 2048, 1024);
    final_comb<<<2048, 256, 0, stream>>>(f2p, 2, b2, x2, out);
  } else {
    gemm_bt<1><<<dim3(32, 4), 256, 0, stream>>>(gbuf, w2T, b2, x2, out, 4096, 512, 2048);
  }
}

// Round 5
// 161.503 us; speedup vs baseline: 2.4988x; 1.0028x over previous
//
#include <hip/hip_runtime.h>
#include <hip/hip_bf16.h>
#include <stdint.h>

typedef __bf16 bf16;
typedef __bf16 bf16x4 __attribute__((ext_vector_type(4)));
typedef __bf16 bf16x8 __attribute__((ext_vector_type(8)));
typedef float  f32x4  __attribute__((ext_vector_type(4)));
typedef float  f32x16 __attribute__((ext_vector_type(16)));

#define MFMA16(A_, B_, C_) __builtin_amdgcn_mfma_f32_16x16x32_bf16((A_), (B_), (C_), 0, 0, 0)
#define MFMA32(A_, B_, C_) __builtin_amdgcn_mfma_f32_32x32x16_bf16((A_), (B_), (C_), 0, 0, 0)

#define QSCALE 0.1803368801111137f  // 0.125 * log2(e), folded into Wq/bq

__device__ __forceinline__ void gload_lds16(const void* g, void* l) {
  __builtin_amdgcn_global_load_lds(
      (const __attribute__((address_space(1))) unsigned int*)g,
      (__attribute__((address_space(3))) unsigned int*)l, 16, 0, 0);
}

__device__ __forceinline__ unsigned pk2(float lo, float hi_) {
  union { bf16 h[2]; unsigned u; } t;
  t.h[0] = (bf16)lo; t.h[1] = (bf16)hi_;
  return t.u;
}

__device__ __forceinline__ float fast_exp2(float x) {
#if __has_builtin(__builtin_amdgcn_exp2f)
  return __builtin_amdgcn_exp2f(x);
#else
  return exp2f(x);
#endif
}

// ---------------------------------------------------------------------------
// prep: all weight transposes (fp32->bf16, out[n][k]=in[k][n]*scale) + bias pack
// ---------------------------------------------------------------------------
__global__ __launch_bounds__(256) void prep(const float* __restrict__ Wq,
                                            const float* __restrict__ Wk,
                                            const float* __restrict__ Wv,
                                            const float* __restrict__ Wo,
                                            const float* __restrict__ W1,
                                            const float* __restrict__ W2,
                                            const float* __restrict__ bq,
                                            const float* __restrict__ bk,
                                            const float* __restrict__ bv,
                                            bf16* __restrict__ wqkvT, bf16* __restrict__ woT,
                                            bf16* __restrict__ w1T, bf16* __restrict__ w2T,
                                            float* __restrict__ bqkv) {
  const int b = blockIdx.x;
  if (b >= 768) {
    int i = (b - 768) * 256 + threadIdx.x;
    if (i < 1536)
      bqkv[i] = (i < 512) ? bq[i] * QSCALE : (i < 1024 ? bk[i - 512] : bv[i - 1024]);
    return;
  }
  const float* in; bf16* outp; int K, N, t; float sc = 1.f;
  if (b < 64)       { in = Wq; outp = wqkvT;              K = 512;  N = 512;  t = b;       sc = QSCALE; }
  else if (b < 128) { in = Wk; outp = wqkvT + 512 * 512;  K = 512;  N = 512;  t = b - 64;  }
  else if (b < 192) { in = Wv; outp = wqkvT + 1024 * 512; K = 512;  N = 512;  t = b - 128; }
  else if (b < 256) { in = Wo; outp = woT;                K = 512;  N = 512;  t = b - 192; }
  else if (b < 512) { in = W1; outp = w1T;                K = 512;  N = 2048; t = b - 256; }
  else              { in = W2; outp = w2T;                K = 2048; N = 512;  t = b - 512; }
  const int tx = K >> 6;
  const int k0 = (t % tx) * 64, n0 = (t / tx) * 64;
  __shared__ bf16 tile[64][72];
  const int tid = threadIdx.x;
#pragma unroll
  for (int s = 0; s < 16; ++s) {
    int j = tid + s * 256;
    int r = j >> 6, c = j & 63;
    tile[r][c] = (bf16)(in[(size_t)(k0 + r) * N + n0 + c] * sc);
  }
  __syncthreads();
#pragma unroll
  for (int s = 0; s < 16; ++s) {
    int j = tid + s * 256;
    int n = j >> 6, k = j & 63;
    outp[(size_t)(n0 + n) * K + k0 + k] = tile[k][n];
  }
}

// ---------------------------------------------------------------------------
// LayerNorm: x fp32 [4096][512] -> out bf16. One wave per row.
// ---------------------------------------------------------------------------
__global__ __launch_bounds__(256) void ln_k(const float* __restrict__ x,
                                            const float* __restrict__ sc,
                                            const float* __restrict__ bi,
                                            bf16* __restrict__ out) {
  const int w = threadIdx.x >> 6, l = threadIdx.x & 63;
  const int row = blockIdx.x * 4 + w;
  const float4* xp = (const float4*)(x + (size_t)row * 512 + l * 8);
  float4 v0 = xp[0], v1 = xp[1];
  float xv[8] = {v0.x, v0.y, v0.z, v0.w, v1.x, v1.y, v1.z, v1.w};
  float s = 0.f, q = 0.f;
#pragma unroll
  for (int j = 0; j < 8; ++j) { s += xv[j]; q += xv[j] * xv[j]; }
#pragma unroll
  for (int m = 1; m < 64; m <<= 1) { s += __shfl_xor(s, m); q += __shfl_xor(q, m); }
  const float mean = s * (1.f / 512.f);
  const float var = q * (1.f / 512.f) - mean * mean;
  const float rstd = rsqrtf(var + 1e-6f);
  const float4* scp = (const float4*)(sc + l * 8);
  const float4* bip = (const float4*)(bi + l * 8);
  float4 s0 = scp[0], s1 = scp[1], b0 = bip[0], b1 = bip[1];
  float sv[8] = {s0.x, s0.y, s0.z, s0.w, s1.x, s1.y, s1.z, s1.w};
  float bv[8] = {b0.x, b0.y, b0.z, b0.w, b1.x, b1.y, b1.z, b1.w};
  bf16x8 ov;
#pragma unroll
  for (int j = 0; j < 8; ++j) ov[j] = (bf16)((xv[j] - mean) * rstd * sv[j] + bv[j]);
  *(bf16x8*)(out + (size_t)row * 512 + l * 8) = ov;
}

// ---------------------------------------------------------------------------
// ln2_comb: x2 = p0+p1+bo+x (fp32), h2 = LN(x2) (bf16)
// ---------------------------------------------------------------------------
__global__ __launch_bounds__(256) void ln2_comb(const float* __restrict__ p0,
                                                const float* __restrict__ p1,
                                                const float* __restrict__ x,
                                                const float* __restrict__ bo,
                                                const float* __restrict__ sc,
                                                const float* __restrict__ bi,
                                                float* __restrict__ x2,
                                                bf16* __restrict__ h2) {
  const int w = threadIdx.x >> 6, l = threadIdx.x & 63;
  const int row = blockIdx.x * 4 + w;
  const size_t base = (size_t)row * 512 + l * 8;
  float xv[8];
#pragma unroll
  for (int j = 0; j < 2; ++j) {
    float4 a = *(const float4*)(p0 + base + j * 4);
    float4 b = *(const float4*)(p1 + base + j * 4);
    float4 c = *(const float4*)(x + base + j * 4);
    float4 d = *(const float4*)(bo + l * 8 + j * 4);
    xv[j * 4 + 0] = a.x + b.x + c.x + d.x;
    xv[j * 4 + 1] = a.y + b.y + c.y + d.y;
    xv[j * 4 + 2] = a.z + b.z + c.z + d.z;
    xv[j * 4 + 3] = a.w + b.w + c.w + d.w;
  }
  *(float4*)(x2 + base) = make_float4(xv[0], xv[1], xv[2], xv[3]);
  *(float4*)(x2 + base + 4) = make_float4(xv[4], xv[5], xv[6], xv[7]);
  float s = 0.f, q = 0.f;
#pragma unroll
  for (int j = 0; j < 8; ++j) { s += xv[j]; q += xv[j] * xv[j]; }
#pragma unroll
  for (int m = 1; m < 64; m <<= 1) { s += __shfl_xor(s, m); q += __shfl_xor(q, m); }
  const float mean = s * (1.f / 512.f);
  const float var = q * (1.f / 512.f) - mean * mean;
  const float rstd = rsqrtf(var + 1e-6f);
  const float4* scp = (const float4*)(sc + l * 8);
  const float4* bip = (const float4*)(bi + l * 8);
  float4 s0 = scp[0], s1 = scp[1], b0 = bip[0], b1 = bip[1];
  float sv[8] = {s0.x, s0.y, s0.z, s0.w, s1.x, s1.y, s1.z, s1.w};
  float bv[8] = {b0.x, b0.y, b0.z, b0.w, b1.x, b1.y, b1.z, b1.w};
  bf16x8 ov;
#pragma unroll
  for (int j = 0; j < 8; ++j) ov[j] = (bf16)((xv[j] - mean) * rstd * sv[j] + bv[j]);
  *(bf16x8*)(h2 + base) = ov;
}

// out = sum(parts) + b2 + x2   (all fp32)
__global__ __launch_bounds__(256) void final_comb(const float* __restrict__ parts, int nsplit,
                                                  const float* __restrict__ b2,
                                                  const float* __restrict__ x2,
                                                  float* __restrict__ outp) {
  const int i4 = blockIdx.x * 256 + threadIdx.x;
  const size_t off = (size_t)i4 * 4;
  float4 acc = *(const float4*)(x2 + off);
  float4 bb = *(const float4*)(b2 + (off & 511));
  acc.x += bb.x; acc.y += bb.y; acc.z += bb.z; acc.w += bb.w;
  for (int z = 0; z < nsplit; ++z) {
    float4 p = *(const float4*)(parts + (size_t)z * 4096 * 512 + off);
    acc.x += p.x; acc.y += p.y; acc.z += p.z; acc.w += p.w;
  }
  *(float4*)(outp + off) = acc;
}

// ---------------------------------------------------------------------------
// GEMM core, BK=64, XOR-swizzled LDS.
// ---------------------------------------------------------------------------
template <int EPI>
__global__ __launch_bounds__(256) void gemm_bt(const bf16* __restrict__ A,
                                               const bf16* __restrict__ Bt,
                                               const float* __restrict__ bias,
                                               const float* __restrict__ res,
                                               void* __restrict__ outp,
                                               int M, int N, int K) {
  __shared__ bf16 a_lds[128 * 64];
  __shared__ bf16 b_lds[128 * 64];
  const int m0 = blockIdx.x * 128, n0 = blockIdx.y * 128;
  const int tid = threadIdx.x, l = tid & 63, w = tid >> 6;
  const int wm = w >> 1, wn = w & 1;
  const int lc = l & 15, g = l >> 4;
  const int srow = l >> 3;
  const int cs = (l & 7) ^ srow;

  f32x4 acc[4][4] = {};
  const int kiters = K >> 6;
  for (int kt = 0; kt < kiters; ++kt) {
    const int k0 = kt << 6;
#pragma unroll
    for (int r = 0; r < 4; ++r) {
      const int rg = r * 32 + w * 8;
      gload_lds16(A + (size_t)(m0 + rg + srow) * K + k0 + cs * 8,
                  (char*)a_lds + rg * 128);
      gload_lds16(Bt + (size_t)(n0 + rg + srow) * K + k0 + cs * 8,
                  (char*)b_lds + rg * 128);
    }
    __syncthreads();
#pragma unroll
    for (int kk = 0; kk < 2; ++kk) {
      bf16x8 af[4], bfr[4];
#pragma unroll
      for (int i = 0; i < 4; ++i) {
        const int sw = ((kk * 4 + g) ^ (lc & 7)) * 8;
        af[i]  = *(const bf16x8*)(a_lds + (wm * 64 + i * 16 + lc) * 64 + sw);
        bfr[i] = *(const bf16x8*)(b_lds + (wn * 64 + i * 16 + lc) * 64 + sw);
      }
#pragma unroll
      for (int mi = 0; mi < 4; ++mi)
#pragma unroll
        for (int ni = 0; ni < 4; ++ni)
          acc[mi][ni] = MFMA16(af[mi], bfr[ni], acc[mi][ni]);
    }
    __syncthreads();
  }

#pragma unroll
  for (int mi = 0; mi < 4; ++mi)
#pragma unroll
    for (int ni = 0; ni < 4; ++ni) {
      const int col = n0 + wn * 64 + ni * 16 + lc;
      const float bb = bias[col];
#pragma unroll
      for (int i = 0; i < 4; ++i) {
        const int row = m0 + wm * 64 + mi * 16 + g * 4 + i;
        float v = acc[mi][ni][i] + bb;
        if constexpr (EPI == 0) {
          ((bf16*)outp)[(size_t)row * N + col] = (bf16)v;
        } else if constexpr (EPI == 1) {
          ((float*)outp)[(size_t)row * N + col] = v + res[(size_t)row * N + col];
        } else {
          float t = -2.3022077697f * (v + 0.044715f * v * v * v);
          float gl = v / (1.f + fast_exp2(t));
          ((bf16*)outp)[(size_t)row * N + col] = (bf16)gl;
        }
      }
    }
}

// ---------------------------------------------------------------------------
// Split-K GEMM partial (BK=64, swizzled): parts[kz][M][N] raw f32
// ---------------------------------------------------------------------------
__global__ __launch_bounds__(256) void gemm_skp(const bf16* __restrict__ A,
                                                const bf16* __restrict__ Bt,
                                                float* __restrict__ parts,
                                                int M, int N, int Kstride, int Kc) {
  __shared__ bf16 a_lds[128 * 64];
  __shared__ bf16 b_lds[128 * 64];
  const int m0 = blockIdx.x * 128, n0 = blockIdx.y * 128, kz = blockIdx.z;
  A += (size_t)kz * Kc;
  Bt += (size_t)kz * Kc;
  float* outp = parts + (size_t)kz * M * N;
  const int tid = threadIdx.x, l = tid & 63, w = tid >> 6;
  const int wm = w >> 1, wn = w & 1;
  const int lc = l & 15, g = l >> 4;
  const int srow = l >> 3;
  const int cs = (l & 7) ^ srow;

  f32x4 acc[4][4] = {};
  const int kiters = Kc >> 6;
  for (int kt = 0; kt < kiters; ++kt) {
    const int k0 = kt << 6;
#pragma unroll
    for (int r = 0; r < 4; ++r) {
      const int rg = r * 32 + w * 8;
      gload_lds16(A + (size_t)(m0 + rg + srow) * Kstride + k0 + cs * 8,
                  (char*)a_lds + rg * 128);
      gload_lds16(Bt + (size_t)(n0 + rg + srow) * Kstride + k0 + cs * 8,
                  (char*)b_lds + rg * 128);
    }
    __syncthreads();
#pragma unroll
    for (int kk = 0; kk < 2; ++kk) {
      bf16x8 af[4], bfr[4];
#pragma unroll
      for (int i = 0; i < 4; ++i) {
        const int sw = ((kk * 4 + g) ^ (lc & 7)) * 8;
        af[i]  = *(const bf16x8*)(a_lds + (wm * 64 + i * 16 + lc) * 64 + sw);
        bfr[i] = *(const bf16x8*)(b_lds + (wn * 64 + i * 16 + lc) * 64 + sw);
      }
#pragma unroll
      for (int mi = 0; mi < 4; ++mi)
#pragma unroll
        for (int ni = 0; ni < 4; ++ni)
          acc[mi][ni] = MFMA16(af[mi], bfr[ni], acc[mi][ni]);
    }
    __syncthreads();
  }

#pragma unroll
  for (int mi = 0; mi < 4; ++mi)
#pragma unroll
    for (int ni = 0; ni < 4; ++ni) {
      const int col = n0 + wn * 64 + ni * 16 + lc;
#pragma unroll
      for (int i = 0; i < 4; ++i) {
        const int row = m0 + wm * 64 + mi * 16 + g * 4 + i;
        outp[(size_t)row * N + col] = acc[mi][ni][i];
      }
    }
}

// ---------------------------------------------------------------------------
// V transpose: qkv[t][1024 + h*64 + d] -> vt[h][d][t]   (bf16)
// ---------------------------------------------------------------------------
__global__ __launch_bounds__(256) void vtrans(const bf16* __restrict__ qkv,
                                              bf16* __restrict__ vt) {
  __shared__ bf16 tile[64][72];
  const int t0 = blockIdx.x * 64;
  const int head = blockIdx.y;
  const int tid = threadIdx.x;
#pragma unroll
  for (int s = 0; s < 16; ++s) {
    int j = tid + s * 256;
    int t = j >> 6, c = j & 63;
    tile[t][c] = qkv[(size_t)(t0 + t) * 1536 + 1024 + head * 64 + c];
  }
  __syncthreads();
#pragma unroll
  for (int s = 0; s < 16; ++s) {
    int j = tid + s * 256;
    int d = j >> 6, t = j & 63;
    vt[(size_t)head * 64 * 4096 + (size_t)d * 4096 + t0 + t] = tile[t][d];
  }
}

// ---------------------------------------------------------------------------
// Flash attention v5: wave-private double-buffered tiles, NO main-loop
// barriers, counted vmcnt pipelining, 32x32x16 swapped-operand MFMA,
// in-register constant-max softmax (scale pre-folded into Wq/bq).
// Grid 512 = qt(64) x head(8). Block: 4 waves; wave w: q-half (w&1),
// key-half (w>>1, 2048 keys in 64 tiles of 32). LDS 16KB/wave:
//   K tile [32 keys][128B dims], paired-V tile [32 rows][128B]
//   (row r = Vt[d=r][32 keys] | Vt[d=32+r][32 keys]), both ^(row&7) chunk
//   swizzle (conflict-free pattern, measured 0 in R2).
// ---------------------------------------------------------------------------
__global__ __launch_bounds__(256, 2) void attn_k(const bf16* __restrict__ qkv,
                                                 const bf16* __restrict__ vt,
                                                 bf16* __restrict__ out) {
  const int bid = blockIdx.x;
  const int head = bid & 7;      // one head per XCD (L2 locality)
  const int qt = bid >> 3;       // 0..63
  const int w = threadIdx.x >> 6, l = threadIdx.x & 63;
  const int hi = l >> 5, l5 = l & 31;
  const int pair = w >> 1, wq = w & 1;

  __shared__ __align__(16) char smem[65536];
  char* kt_l = smem + w * 16384;     // [2][4096] B
  char* vt_l = kt_l + 8192;          // [2][4096] B

  const bf16* kg = qkv + 512 + head * 64;          // K rows, stride 1536
  const bf16* vg = vt + (size_t)head * 64 * 4096;  // Vt rows (d), stride 4096

  // Q fragments (Wq pre-scaled): qf[cc] = Q[q=l5][cc*16 + hi*8 + 0..7]
  const int qrow0 = qt * 64 + wq * 32;
  const bf16* qb = qkv + (size_t)(qrow0 + l5) * 1536 + head * 64;
  bf16x8 qf[4];
#pragma unroll
  for (int cc = 0; cc < 4; ++cc) qf[cc] = *(const bf16x8*)(qb + cc * 16 + hi * 8);

  const int kstart = pair * 2048;
  const int srow = l >> 3;            // staging row within 8-row group
  const int cl = (l & 7) ^ srow;      // logical chunk (pre-swizzled source)
  const bf16* kgl = kg + (size_t)(kstart + srow) * 1536 + cl * 8;
  const bf16* vgl = vg + (size_t)((cl >> 2) * 32 + srow) * 4096 + kstart + (cl & 3) * 8;

#define STAGE_A(T_, B_)                                                     \
  do {                                                                      \
    const int kv0_ = (T_) * 32;                                             \
    _Pragma("unroll")                                                       \
    for (int j_ = 0; j_ < 4; ++j_) {                                        \
      gload_lds16(kgl + (size_t)(kv0_ + j_ * 8) * 1536,                     \
                  kt_l + (B_) * 4096 + j_ * 1024);                          \
      gload_lds16(vgl + (size_t)(j_ * 8) * 4096 + kv0_,                     \
                  vt_l + (B_) * 4096 + j_ * 1024);                          \
    }                                                                       \
  } while (0)

  STAGE_A(0, 0);

  f32x16 o0 = {}, o1 = {};
  float psum = 0.f;
  const int swl = l5 & 7;

  for (int t = 0; t < 64; ++t) {
    const int cur = t & 1;
    if (t < 63) {
      STAGE_A(t + 1, cur ^ 1);
      asm volatile("s_waitcnt vmcnt(8)" ::: "memory");
    } else {
      asm volatile("s_waitcnt vmcnt(0)" ::: "memory");
    }
    const bf16* kb = (const bf16*)(kt_l + cur * 4096);
    const bf16* vb = (const bf16*)(vt_l + cur * 4096);

    __builtin_amdgcn_s_setprio(1);
    // QK^T: S^T[key][q], lane(q=l5,hi) holds 16 keys
    f32x16 s = {};
#pragma unroll
    for (int cc = 0; cc < 4; ++cc) {
      bf16x8 kf = *(const bf16x8*)(kb + l5 * 64 + (((cc * 2 + hi) ^ swl) * 8));
      s = MFMA32(kf, qf[cc], s);
    }

    // softmax + pack + PV per 16-key chunk
#pragma unroll
    for (int c = 0; c < 2; ++c) {
      float p[8];
#pragma unroll
      for (int j = 0; j < 8; ++j) p[j] = fast_exp2(s[c * 8 + j]);
      psum += ((p[0] + p[1]) + (p[2] + p[3])) + ((p[4] + p[5]) + (p[6] + p[7]));
      unsigned X = pk2(p[0], p[1]), X2 = pk2(p[2], p[3]);
      unsigned Y = pk2(p[4], p[5]), Y2 = pk2(p[6], p[7]);
      asm volatile("v_permlane32_swap_b32 %0, %1" : "+v"(X), "+v"(Y));
      asm volatile("v_permlane32_swap_b32 %0, %1" : "+v"(X2), "+v"(Y2));
      union { unsigned wd[4]; bf16x8 v; } pa;
      pa.wd[0] = X; pa.wd[1] = X2; pa.wd[2] = Y; pa.wd[3] = Y2;
      bf16x8 vf0 = *(const bf16x8*)(vb + l5 * 64 + (((c * 2 + hi) ^ swl) * 8));
      bf16x8 vf1 = *(const bf16x8*)(vb + l5 * 64 + (((4 + c * 2 + hi) ^ swl) * 8));
      o0 = MFMA32(vf0, pa.v, o0);
      o1 = MFMA32(vf1, pa.v, o1);
    }
    __builtin_amdgcn_s_setprio(0);
  }
#undef STAGE_A

  // combine the two key-half partials via LDS (tiles dead)
  __syncthreads();
  float* comb = (float*)smem;   // 2*64*33*4 = 16896 B
  if (w >= 2) {
    float* cb = comb + ((w - 2) * 64 + l) * 33;
#pragma unroll
    for (int r = 0; r < 16; ++r) { cb[r] = o0[r]; cb[16 + r] = o1[r]; }
    cb[32] = psum;
  }
  __syncthreads();
  if (w < 2) {
    const float* cb = comb + (w * 64 + l) * 33;
#pragma unroll
    for (int r = 0; r < 16; ++r) { o0[r] += cb[r]; o1[r] += cb[16 + r]; }
    psum += cb[32];
    const float lsum = psum + __shfl_xor(psum, 32);
    const float inv = 1.f / lsum;
    bf16* ob = out + (size_t)(qrow0 + l5) * 512 + head * 64;
#pragma unroll
    for (int dt = 0; dt < 2; ++dt)
#pragma unroll
      for (int rg = 0; rg < 4; ++rg) {
        bf16x4 vv;
#pragma unroll
        for (int e = 0; e < 4; ++e) {
          const float ov = (dt == 0) ? o0[rg * 4 + e] : o1[rg * 4 + e];
          vv[e] = (bf16)(ov * inv);
        }
        *(bf16x4*)(ob + dt * 32 + rg * 8 + hi * 4) = vv;
      }
  }
}

// ---------------------------------------------------------------------------
extern "C" void kernel_launch(void* const* d_in, const int* in_sizes, int n_in,
                              void* d_out, int out_size, void* d_ws, size_t ws_size,
                              hipStream_t stream) {
  const float* x    = (const float*)d_in[0];
  const float* ln1s = (const float*)d_in[1];
  const float* ln1b = (const float*)d_in[2];
  const float* Wq   = (const float*)d_in[3];
  const float* bq   = (const float*)d_in[4];
  const float* Wk   = (const float*)d_in[5];
  const float* bk   = (const float*)d_in[6];
  const float* Wv   = (const float*)d_in[7];
  const float* bv   = (const float*)d_in[8];
  const float* Wo   = (const float*)d_in[9];
  const float* bo   = (const float*)d_in[10];
  const float* ln2s = (const float*)d_in[11];
  const float* ln2b = (const float*)d_in[12];
  const float* W1   = (const float*)d_in[13];
  const float* b1   = (const float*)d_in[14];
  const float* W2   = (const float*)d_in[15];
  const float* b2   = (const float*)d_in[16];
  float* out = (float*)d_out;

  char* ws = (char*)d_ws;
  bf16*  wqkvT = (bf16*)(ws + 0);          // [1536][512] 1.5M
  bf16*  woT   = (bf16*)(ws + 1572864);    // [512][512]  0.5M
  bf16*  w1T   = (bf16*)(ws + 2097152);    // [2048][512] 2M
  bf16*  w2T   = (bf16*)(ws + 4194304);    // [512][2048] 2M
  float* bqkv  = (float*)(ws + 6291456);   // 6144 B
  float* x2    = (float*)(ws + 6559744);   // [4096][512] f32 8M
  bf16*  h     = (bf16*)(ws + 14948352);   // 4M; shared by h / attnb / h2
  bf16*  qkv   = (bf16*)(ws + 19142656);   // [4096][1536] 12M
  bf16*  vt    = (bf16*)(ws + 31725568);   // [8][64][4096] 4M  (end 35919872)
  bf16*  attnb = h;
  bf16*  h2    = h;
  float* wop   = (float*)(ws + 19142656);  // 2x8M f32 over dead qkv+vt
  bf16*  gbuf  = qkv;                      // ffn1 out 16M over dead wop region
  float* f2p   = (float*)(ws + 35919872);  // gated
  const size_t need4 = 35919872 + 4ull * 8388608;
  const size_t need2 = 35919872 + 2ull * 8388608;

  prep<<<774, 256, 0, stream>>>(Wq, Wk, Wv, Wo, W1, W2, bq, bk, bv,
                                wqkvT, woT, w1T, w2T, bqkv);

  ln_k<<<1024, 256, 0, stream>>>(x, ln1s, ln1b, h);
  gemm_bt<0><<<dim3(32, 12), 256, 0, stream>>>(h, wqkvT, bqkv, nullptr, qkv, 4096, 1536, 512);
  vtrans<<<dim3(64, 8), 256, 0, stream>>>(qkv, vt);
  attn_k<<<512, 256, 0, stream>>>(qkv, vt, attnb);
  gemm_skp<<<dim3(32, 4, 2), 256, 0, stream>>>(attnb, woT, wop, 4096, 512, 512, 256);
  ln2_comb<<<1024, 256, 0, stream>>>(wop, wop + 4096 * 512, x, bo, ln2s, ln2b, x2, h2);
  gemm_bt<2><<<dim3(32, 16), 256, 0, stream>>>(h2, w1T, b1, nullptr, gbuf, 4096, 2048, 512);
  if (ws_size >= need4) {
    gemm_skp<<<dim3(32, 4, 4), 256, 0, stream>>>(gbuf, w2T, f2p, 4096, 512, 2048, 512);
    final_comb<<<2048, 256, 0, stream>>>(f2p, 4, b2, x2, out);
  } else if (ws_size >= need2) {
    gemm_skp<<<dim3(32, 4, 2), 256, 0, stream>>>(gbuf, w2T, f2p, 4096, 512, 2048, 1024);
    final_comb<<<2048, 256, 0, stream>>>(f2p, 2, b2, x2, out);
  } else {
    gemm_bt<1><<<dim3(32, 4), 256, 0, stream>>>(gbuf, w2T, b2, x2, out, 4096, 512, 2048);
  }
}